// Round 1
// baseline (30948.260 us; speedup 1.0000x reference)
//
#include <hip/hip_runtime.h>
#include <cstdint>
#include <cstddef>

typedef __attribute__((ext_vector_type(8))) short s8v;          // 8 bf16
typedef __attribute__((ext_vector_type(4))) float f4v;
typedef __attribute__((ext_vector_type(4))) unsigned int u4v;

#define DEVFN __device__ __forceinline__

DEVFN unsigned short f2bf(float f) {
    unsigned int u = __builtin_bit_cast(unsigned int, f);
    return (unsigned short)((u + 0x7FFFu + ((u >> 16) & 1u)) >> 16);
}
DEVFN float bf2f(unsigned short h) {
    unsigned int u = ((unsigned int)h) << 16;
    return __builtin_bit_cast(float, u);
}
DEVFN float sigm(float x) { return 1.0f / (1.0f + __expf(-x)); }
DEVFN float tanh_fast(float x) { float e = __expf(2.0f * x); return 1.0f - 2.0f / (e + 1.0f); }

DEVFN u4v pack8(const unsigned short o[8]) {
    u4v v;
    v[0] = (unsigned)o[0] | ((unsigned)o[1] << 16);
    v[1] = (unsigned)o[2] | ((unsigned)o[3] << 16);
    v[2] = (unsigned)o[4] | ((unsigned)o[5] << 16);
    v[3] = (unsigned)o[6] | ((unsigned)o[7] << 16);
    return v;
}

// ---------------- geometry ----------------
constexpr int BB = 32, SS = 1024, II = 512, HH = 1024;
constexpr int NCOL = 6144;  // 2 dirs x (2048 gate cols + 1024 n cols)

constexpr size_t OFF_X    = 0;                       // bf16 x   [32768][512]
constexpr size_t SZ_X     = (size_t)BB * SS * II * 2;
constexpr size_t OFF_WINT = OFF_X + SZ_X;            // bf16 WinT [6144][512]  (K-contiguous)
constexpr size_t SZ_WINT  = (size_t)NCOL * II * 2;
constexpr size_t OFF_WREC = OFF_WINT + SZ_WINT;      // bf16 Wrec [2][3072][1024] (K-contiguous)
constexpr size_t SZ_WREC  = (size_t)2 * 3072 * HH * 2;
constexpr size_t OFF_BIAS = OFF_WREC + SZ_WREC;      // f32 [6144]
constexpr size_t SZ_BIAS  = (size_t)NCOL * 4;
constexpr size_t OFF_H    = OFF_BIAS + SZ_BIAS;      // bf16 h ping-pong [2 dir][2 buf][32][1024]
constexpr size_t SZ_H     = (size_t)2 * 2 * BB * HH * 2;
constexpr size_t OFF_BAR  = OFF_H + SZ_H;            // barrier counters
constexpr size_t SZ_BAR   = 2048;
constexpr size_t OFF_G    = OFF_BAR + SZ_BAR;        // bf16 G [1024][32][6144]
constexpr size_t SZ_G     = (size_t)SS * BB * NCOL * 2;
constexpr size_t WS_NEED  = OFF_G + SZ_G;            // ~455 MB

// =====================================================================
// prep: f32->bf16 conversions + weight transposes + fused bias vector
// =====================================================================
__global__ void prep_kernel(
    const float* __restrict__ x,
    const float* __restrict__ Wi, const float* __restrict__ Wni,
    const float* __restrict__ Winvi, const float* __restrict__ Wninvi,
    const float* __restrict__ Wh, const float* __restrict__ Wnh,
    const float* __restrict__ Winvh, const float* __restrict__ Wninvh,
    const float* __restrict__ Bg, const float* __restrict__ Bni,
    const float* __restrict__ Binv, const float* __restrict__ Bninvi,
    unsigned short* __restrict__ xb, unsigned short* __restrict__ WinT,
    unsigned short* __restrict__ Wrec, float* __restrict__ bias)
{
    constexpr int NX8  = (BB * SS * II) / 8;       // 2,097,152
    constexpr int NWI8 = (NCOL * II) / 8;          //   393,216
    constexpr int NWR8 = (2 * 3072 * HH) / 8;      //   786,432
    constexpr int TOT  = NX8 + NWI8 + NWR8 + NCOL;
    for (int i = blockIdx.x * blockDim.x + threadIdx.x; i < TOT;
         i += gridDim.x * blockDim.x) {
        if (i < NX8) {
            const float* sp = x + (size_t)i * 8;
            unsigned short o[8];
#pragma unroll
            for (int j = 0; j < 8; ++j) o[j] = f2bf(sp[j]);
            *(u4v*)(xb + (size_t)i * 8) = pack8(o);
        } else if (i < NX8 + NWI8) {
            int u = i - NX8;
            int n = u >> 6, k0 = (u & 63) * 8;
            const float* src; int stride;
            if (n < 2048)      { src = Wi + n;            stride = 2048; }
            else if (n < 3072) { src = Wni + (n - 2048);  stride = 1024; }
            else if (n < 5120) { src = Winvi + (n - 3072); stride = 2048; }
            else               { src = Wninvi + (n - 5120); stride = 1024; }
            unsigned short o[8];
#pragma unroll
            for (int j = 0; j < 8; ++j) o[j] = f2bf(src[(size_t)(k0 + j) * stride]);
            *(u4v*)(WinT + (size_t)n * 512 + k0) = pack8(o);
        } else if (i < NX8 + NWI8 + NWR8) {
            int u = i - NX8 - NWI8;
            int R = u >> 7, k0 = (u & 127) * 8;
            int dir = R / 3072, n = R % 3072;
            const float* src; int stride;
            if (n < 2048) { src = (dir ? Winvh : Wh) + n;          stride = 2048; }
            else          { src = (dir ? Wninvh : Wnh) + (n - 2048); stride = 1024; }
            unsigned short o[8];
#pragma unroll
            for (int j = 0; j < 8; ++j) o[j] = f2bf(src[(size_t)(k0 + j) * stride]);
            *(u4v*)(Wrec + (size_t)R * 1024 + k0) = pack8(o);
        } else {
            int c = i - NX8 - NWI8 - NWR8;
            int dir = c / 3072, cc = c % 3072;
            bias[c] = (cc < 2048) ? (dir ? Binv : Bg)[cc]
                                  : (dir ? Bninvi : Bni)[cc - 2048];
        }
    }
}

// =====================================================================
// gemm_in: G[s*32+b][n] = bf16( x[b,s,:] @ Win[:,n] + bias[n] )
// M=32768 K=512 N=6144, 128x128 tiles, BK=64, global_load_lds + XOR swizzle
// =====================================================================
#define GLL16(gp, lp) __builtin_amdgcn_global_load_lds( \
    (const __attribute__((address_space(1))) void*)(gp), \
    (__attribute__((address_space(3))) void*)(lp), 16, 0, 0)

__global__ __launch_bounds__(256, 2) void gemm_in(
    const unsigned short* __restrict__ xb,
    const unsigned short* __restrict__ WinT,
    const float* __restrict__ bias,
    unsigned short* __restrict__ G)
{
    __shared__ char smem[32768];
    char* As = smem;
    char* Bs = smem + 16384;
    const int tid = threadIdx.x, lane = tid & 63, wid = tid >> 6;
    int wg = blockIdx.x;
    int swz = (wg & 7) * 1536 + (wg >> 3);   // 12288 = 8*1536, bijective XCD swizzle
    const int m0 = (swz & 255) * 128, n0 = (swz >> 8) * 128;
    const int l15 = lane & 15, hi = lane >> 4;
    const int mw = (wid & 1) * 64, nw = (wid >> 1) * 64;

    f4v acc[4][4] = {};

    const char* xrow = (const char*)xb;    // row stride 1024 B
    const char* wrow = (const char*)WinT;  // row stride 1024 B

    for (int kt = 0; kt < 8; ++kt) {
        const int kb0 = kt * 128;
#pragma unroll
        for (int r = 0; r < 4; ++r) {
            int q = wid * 4 + r;
            int o = q * 1024 + lane * 16;
            int row = o >> 7;
            int kbs = (o ^ ((row & 7) << 4)) & 127;   // inverse-swizzled source
            GLL16(xrow + (size_t)(m0 + row) * 1024 + kb0 + kbs, As + q * 1024);
            GLL16(wrow + (size_t)(n0 + row) * 1024 + kb0 + kbs, Bs + q * 1024);
        }
        __syncthreads();
#pragma unroll
        for (int kc = 0; kc < 2; ++kc) {
            s8v a[4], b[4];
#pragma unroll
            for (int mt = 0; mt < 4; ++mt) {
                int row = mw + mt * 16 + l15;
                int off = (row << 7) + kc * 64 + hi * 16;
                a[mt] = *(const s8v*)(As + (off ^ ((row & 7) << 4)));
            }
#pragma unroll
            for (int nt = 0; nt < 4; ++nt) {
                int row = nw + nt * 16 + l15;
                int off = (row << 7) + kc * 64 + hi * 16;
                b[nt] = *(const s8v*)(Bs + (off ^ ((row & 7) << 4)));
            }
#pragma unroll
            for (int mt = 0; mt < 4; ++mt)
#pragma unroll
                for (int nt = 0; nt < 4; ++nt)
                    acc[mt][nt] = __builtin_amdgcn_mfma_f32_16x16x32_bf16(
                        a[mt], b[nt], acc[mt][nt], 0, 0, 0);
        }
        __syncthreads();
    }
    // epilogue: +bias, store bf16 to G[s*32+b][n]
#pragma unroll
    for (int mt = 0; mt < 4; ++mt) {
#pragma unroll
        for (int rg = 0; rg < 4; ++rg) {
            int m = m0 + mw + mt * 16 + hi * 4 + rg;
            int bi = m >> 10, si = m & 1023;
            size_t gbase = (size_t)(si * 32 + bi) * NCOL;
#pragma unroll
            for (int nt = 0; nt < 4; ++nt) {
                int n = n0 + nw + nt * 16 + l15;
                G[gbase + n] = f2bf(acc[mt][nt][rg] + bias[n]);
            }
        }
    }
}

// =====================================================================
// gru_rec: persistent bidirectional GRU recurrence. 256 blocks (1/CU).
// block = (dir, 16-batch group, 16 hidden cols). Weights resident in LDS.
// =====================================================================
__device__ void barrier_arrive_wait(unsigned int* bar, unsigned int tgt, int bid)
{
    unsigned int l = (unsigned)bid & 15u;
    unsigned int v = __hip_atomic_fetch_add(&bar[l * 16], 1u, __ATOMIC_RELEASE,
                                            __HIP_MEMORY_SCOPE_AGENT);
    if ((v & 15u) == 15u) {
        unsigned int r = __hip_atomic_fetch_add(&bar[256], 1u, __ATOMIC_ACQ_REL,
                                                __HIP_MEMORY_SCOPE_AGENT);
        if ((r & 15u) == 15u) {
            __hip_atomic_store(&bar[272], (r >> 4) + 1u, __ATOMIC_RELEASE,
                               __HIP_MEMORY_SCOPE_AGENT);
        }
    }
    while (__hip_atomic_load(&bar[272], __ATOMIC_RELAXED,
                             __HIP_MEMORY_SCOPE_AGENT) < tgt)
        __builtin_amdgcn_s_sleep(1);
}

__global__ __launch_bounds__(256, 1) void gru_rec(
    const unsigned short* __restrict__ G,     // [1024][32][6144]
    const unsigned short* __restrict__ Wrec,  // [2][3072][1024]
    const float* __restrict__ Bnh,
    const float* __restrict__ Bninvh,
    unsigned short* __restrict__ hbuf,        // [2][2][32][1024] bf16
    float* __restrict__ out,                  // [32][1024][2048] + ht [32][2048]
    unsigned int* __restrict__ bar)
{
    extern __shared__ char smem[];
    char* wl = smem;                       // 96 KiB: [48 cols][1024 k] bf16, XOR-swizzled
    float* pl = (float*)(smem + 98304);    // partial sums [4 waves][3 panels][16][17]

    const int tid = threadIdx.x, lane = tid & 63, wid = tid >> 6;
    const int bid = blockIdx.x;
    const int dir = bid >> 7, bg = (bid >> 6) & 1, jg = bid & 63;
    const int jbase = jg * 16, bb = bg * 16;
    const int l15 = lane & 15, hi = lane >> 4;

    // ---- one-time: load 3 weight panels (r,z,n) x [1024][16] into LDS ----
    {
        const char* wsrc = (const char*)Wrec;
        for (int q = 0; q < 24; ++q) {
            int o = (q * 256 + tid) * 16;
            int c = o >> 11;                               // 0..47
            int kb = (o ^ ((c & 7) << 4)) & 2047;          // inverse swizzle
            int n = dir * 3072 + (c >> 4) * 1024 + jbase + (c & 15);
            *(u4v*)(wl + o) = *(const u4v*)(wsrc + (size_t)n * 2048 + kb);
        }
    }
    const int b_l = tid >> 4, j_l = tid & 15;
    const float bnh = (dir ? Bninvh : Bnh)[jbase + j_l];
    __syncthreads();

    const int ks2 = wid * 512;   // this wave's K-slice byte offset (256 elems)
    float h_old = 0.0f;

    // prefetch G row for step 0
    int g0 = dir ? 1023 : 0;
    const unsigned short* gp =
        G + ((size_t)(g0 * 32 + bb + b_l) * NCOL + dir * 3072 + jbase + j_l);
    unsigned short gr = gp[0], gz = gp[1024], gn = gp[2048];

    for (int s = 0; s < 1024; ++s) {
        float rsum = 0.f, zsum = 0.f, nsum = 0.f;
        if (s > 0) {
            const int rbuf = (s & 1) ^ 1;
            const char* hrow = (const char*)hbuf +
                ((size_t)((dir * 2 + rbuf) * 32 + bb + l15)) * 2048 + ks2 + hi * 16;
            s8v af[8];
#pragma unroll
            for (int kc = 0; kc < 8; ++kc) af[kc] = *(const s8v*)(hrow + kc * 64);
            f4v acc[3] = {};
#pragma unroll
            for (int p = 0; p < 3; ++p) {
                int c = p * 16 + l15;
                int cbase = c << 11;
                int sw = (c & 7) << 4;
#pragma unroll
                for (int kc = 0; kc < 8; ++kc) {
                    int off = cbase + ks2 + kc * 64 + hi * 16;
                    s8v bf = *(const s8v*)(wl + (off ^ sw));
                    acc[p] = __builtin_amdgcn_mfma_f32_16x16x32_bf16(
                        af[kc], bf, acc[p], 0, 0, 0);
                }
            }
#pragma unroll
            for (int p = 0; p < 3; ++p)
#pragma unroll
                for (int rg = 0; rg < 4; ++rg)
                    pl[((wid * 3 + p) * 16 + hi * 4 + rg) * 17 + l15] = acc[p][rg];
        }
        __syncthreads();
        if (s > 0) {
#pragma unroll
            for (int w = 0; w < 4; ++w) {
                rsum += pl[((w * 3 + 0) * 16 + b_l) * 17 + j_l];
                zsum += pl[((w * 3 + 1) * 16 + b_l) * 17 + j_l];
                nsum += pl[((w * 3 + 2) * 16 + b_l) * 17 + j_l];
            }
        }
        float rv = sigm(rsum + bf2f(gr));
        float zv = sigm(zsum + bf2f(gz));
        float nv = tanh_fast(bf2f(gn) + rv * (nsum + bnh));
        float hn = (1.0f - zv) * nv + zv * h_old;
        h_old = hn;

        const int wbuf = s & 1;
        hbuf[((size_t)((dir * 2 + wbuf) * 32 + bb + b_l)) * HH + jbase + j_l] = f2bf(hn);
        const int s_out = dir ? (1023 - s) : s;
        out[((size_t)(bb + b_l) * SS + s_out) * 2048 + dir * 1024 + jbase + j_l] = hn;
        if (s == 1023)
            out[(size_t)BB * SS * 2048 + (size_t)(bb + b_l) * 2048 +
                dir * 1024 + jbase + j_l] = hn;

        if (s < 1023) {
            // prefetch next step's G into registers (immutable data, safe pre-barrier)
            int g2 = dir ? (1022 - s) : (s + 1);
            const unsigned short* gp2 =
                G + ((size_t)(g2 * 32 + bb + b_l) * NCOL + dir * 3072 + jbase + j_l);
            gr = gp2[0]; gz = gp2[1024]; gn = gp2[2048];
            __syncthreads();
            if (tid == 0) {
                __threadfence();                       // release: flush L2 -> LLC
                barrier_arrive_wait(bar, (unsigned)(s + 1), bid);
            }
            __syncthreads();
            __threadfence();                           // acquire: invalidate L1/stale L2
        }
    }
}

// =====================================================================
extern "C" void kernel_launch(void* const* d_in, const int* in_sizes, int n_in,
                              void* d_out, int out_size, void* d_ws, size_t ws_size,
                              hipStream_t stream)
{
    if (n_in < 15) return;
    const float* x      = (const float*)d_in[0];
    const float* Wi     = (const float*)d_in[1];
    const float* Wh     = (const float*)d_in[2];
    const float* Bg     = (const float*)d_in[3];
    const float* Wni    = (const float*)d_in[4];
    const float* Wnh    = (const float*)d_in[5];
    const float* Bni    = (const float*)d_in[6];
    const float* Bnh    = (const float*)d_in[7];
    const float* Winvi  = (const float*)d_in[8];
    const float* Winvh  = (const float*)d_in[9];
    const float* Binv   = (const float*)d_in[10];
    const float* Wninvi = (const float*)d_in[11];
    const float* Wninvh = (const float*)d_in[12];
    const float* Bninvi = (const float*)d_in[13];
    const float* Bninvh = (const float*)d_in[14];

    if (ws_size < WS_NEED) {
        // workspace too small: fail visibly but safely (absmax == stub value)
        hipMemsetAsync(d_out, 0, (size_t)out_size * 4, stream);
        return;
    }
    char* ws = (char*)d_ws;
    unsigned short* xb   = (unsigned short*)(ws + OFF_X);
    unsigned short* WinT = (unsigned short*)(ws + OFF_WINT);
    unsigned short* Wrec = (unsigned short*)(ws + OFF_WREC);
    float*          bias = (float*)(ws + OFF_BIAS);
    unsigned short* hbuf = (unsigned short*)(ws + OFF_H);
    unsigned int*   bar  = (unsigned int*)(ws + OFF_BAR);
    unsigned short* G    = (unsigned short*)(ws + OFF_G);

    hipMemsetAsync(ws + OFF_BAR, 0, SZ_BAR, stream);

    prep_kernel<<<4096, 256, 0, stream>>>(
        x, Wi, Wni, Winvi, Wninvi, Wh, Wnh, Winvh, Wninvh,
        Bg, Bni, Binv, Bninvi, xb, WinT, Wrec, bias);

    gemm_in<<<12288, 256, 0, stream>>>(xb, WinT, bias, G);

    const int smem_c = 98304 + 12 * 16 * 17 * 4;   // 111,360 B
    hipFuncSetAttribute(reinterpret_cast<const void*>(&gru_rec),
                        hipFuncAttributeMaxDynamicSharedMemorySize, smem_c);
    gru_rec<<<256, 256, smem_c, stream>>>(
        G, Wrec, Bnh, Bninvh, hbuf, (float*)d_out, bar);
}

// Round 2
// 14684.088 us; speedup vs baseline: 2.1076x; 2.1076x over previous
//
#include <hip/hip_runtime.h>
#include <cstdint>
#include <cstddef>

typedef __attribute__((ext_vector_type(8))) short s8v;          // 8 bf16
typedef __attribute__((ext_vector_type(4))) float f4v;
typedef __attribute__((ext_vector_type(4))) unsigned int u4v;

#define DEVFN __device__ __forceinline__

DEVFN unsigned short f2bf(float f) {
    unsigned int u = __builtin_bit_cast(unsigned int, f);
    return (unsigned short)((u + 0x7FFFu + ((u >> 16) & 1u)) >> 16);
}
DEVFN float bf2f(unsigned short h) {
    unsigned int u = ((unsigned int)h) << 16;
    return __builtin_bit_cast(float, u);
}
DEVFN float sigm(float x) { return 1.0f / (1.0f + __expf(-x)); }
DEVFN float tanh_fast(float x) { float e = __expf(2.0f * x); return 1.0f - 2.0f / (e + 1.0f); }

DEVFN u4v pack8(const unsigned short o[8]) {
    u4v v;
    v[0] = (unsigned)o[0] | ((unsigned)o[1] << 16);
    v[1] = (unsigned)o[2] | ((unsigned)o[3] << 16);
    v[2] = (unsigned)o[4] | ((unsigned)o[5] << 16);
    v[3] = (unsigned)o[6] | ((unsigned)o[7] << 16);
    return v;
}

// device-scope (LLC) write-through store — makes data visible across XCDs
// without any cache-wide fence.
DEVFN void store_wt(unsigned int* p, unsigned int v) {
    asm volatile("global_store_dword %0, %1, off sc0 sc1"
                 :: "v"(p), "v"(v) : "memory");
}

// 8x dwordx4 device-scope loads (bypass stale L1/L2, read from LLC) + drain.
// Single asm block so no instruction can slip between loads and the waitcnt.
DEVFN void load_hrow(const void* p, u4v& a0, u4v& a1, u4v& a2, u4v& a3,
                     u4v& a4, u4v& a5, u4v& a6, u4v& a7) {
    asm volatile(
        "global_load_dwordx4 %0, %8, off sc0 sc1\n\t"
        "global_load_dwordx4 %1, %8, off offset:64 sc0 sc1\n\t"
        "global_load_dwordx4 %2, %8, off offset:128 sc0 sc1\n\t"
        "global_load_dwordx4 %3, %8, off offset:192 sc0 sc1\n\t"
        "global_load_dwordx4 %4, %8, off offset:256 sc0 sc1\n\t"
        "global_load_dwordx4 %5, %8, off offset:320 sc0 sc1\n\t"
        "global_load_dwordx4 %6, %8, off offset:384 sc0 sc1\n\t"
        "global_load_dwordx4 %7, %8, off offset:448 sc0 sc1\n\t"
        "s_waitcnt vmcnt(0)"
        : "=&v"(a0), "=&v"(a1), "=&v"(a2), "=&v"(a3),
          "=&v"(a4), "=&v"(a5), "=&v"(a6), "=&v"(a7)
        : "v"(p)
        : "memory");
}

// ---------------- geometry ----------------
constexpr int BB = 32, SS = 1024, II = 512, HH = 1024;
constexpr int NCOL = 6144;  // 2 dirs x (2048 gate cols + 1024 n cols)

constexpr size_t OFF_X    = 0;                       // bf16 x   [32768][512]
constexpr size_t SZ_X     = (size_t)BB * SS * II * 2;
constexpr size_t OFF_WINT = OFF_X + SZ_X;            // bf16 WinT [6144][512]  (K-contiguous)
constexpr size_t SZ_WINT  = (size_t)NCOL * II * 2;
constexpr size_t OFF_WREC = OFF_WINT + SZ_WINT;      // bf16 Wrec [2][3072][1024] (K-contiguous)
constexpr size_t SZ_WREC  = (size_t)2 * 3072 * HH * 2;
constexpr size_t OFF_BIAS = OFF_WREC + SZ_WREC;      // f32 [6144]
constexpr size_t SZ_BIAS  = (size_t)NCOL * 4;
constexpr size_t OFF_H    = OFF_BIAS + SZ_BIAS;      // bf16 h ping-pong [2 dir][2 buf][32][1024]
constexpr size_t SZ_H     = (size_t)2 * 2 * BB * HH * 2;
constexpr size_t OFF_BAR  = OFF_H + SZ_H;            // flag words [4 groups][64]
constexpr size_t SZ_BAR   = 2048;
constexpr size_t OFF_G    = OFF_BAR + SZ_BAR;        // bf16 G [1024][32][6144]
constexpr size_t SZ_G     = (size_t)SS * BB * NCOL * 2;
constexpr size_t WS_NEED  = OFF_G + SZ_G;            // ~455 MB

// =====================================================================
// prep: f32->bf16 conversions + weight transposes + fused bias vector
// =====================================================================
__global__ void prep_kernel(
    const float* __restrict__ x,
    const float* __restrict__ Wi, const float* __restrict__ Wni,
    const float* __restrict__ Winvi, const float* __restrict__ Wninvi,
    const float* __restrict__ Wh, const float* __restrict__ Wnh,
    const float* __restrict__ Winvh, const float* __restrict__ Wninvh,
    const float* __restrict__ Bg, const float* __restrict__ Bni,
    const float* __restrict__ Binv, const float* __restrict__ Bninvi,
    unsigned short* __restrict__ xb, unsigned short* __restrict__ WinT,
    unsigned short* __restrict__ Wrec, float* __restrict__ bias)
{
    constexpr int NX8  = (BB * SS * II) / 8;       // 2,097,152
    constexpr int NWI8 = (NCOL * II) / 8;          //   393,216
    constexpr int NWR8 = (2 * 3072 * HH) / 8;      //   786,432
    constexpr int TOT  = NX8 + NWI8 + NWR8 + NCOL;
    for (int i = blockIdx.x * blockDim.x + threadIdx.x; i < TOT;
         i += gridDim.x * blockDim.x) {
        if (i < NX8) {
            const float* sp = x + (size_t)i * 8;
            unsigned short o[8];
#pragma unroll
            for (int j = 0; j < 8; ++j) o[j] = f2bf(sp[j]);
            *(u4v*)(xb + (size_t)i * 8) = pack8(o);
        } else if (i < NX8 + NWI8) {
            int u = i - NX8;
            int n = u >> 6, k0 = (u & 63) * 8;
            const float* src; int stride;
            if (n < 2048)      { src = Wi + n;            stride = 2048; }
            else if (n < 3072) { src = Wni + (n - 2048);  stride = 1024; }
            else if (n < 5120) { src = Winvi + (n - 3072); stride = 2048; }
            else               { src = Wninvi + (n - 5120); stride = 1024; }
            unsigned short o[8];
#pragma unroll
            for (int j = 0; j < 8; ++j) o[j] = f2bf(src[(size_t)(k0 + j) * stride]);
            *(u4v*)(WinT + (size_t)n * 512 + k0) = pack8(o);
        } else if (i < NX8 + NWI8 + NWR8) {
            int u = i - NX8 - NWI8;
            int R = u >> 7, k0 = (u & 127) * 8;
            int dir = R / 3072, n = R % 3072;
            const float* src; int stride;
            if (n < 2048) { src = (dir ? Winvh : Wh) + n;          stride = 2048; }
            else          { src = (dir ? Wninvh : Wnh) + (n - 2048); stride = 1024; }
            unsigned short o[8];
#pragma unroll
            for (int j = 0; j < 8; ++j) o[j] = f2bf(src[(size_t)(k0 + j) * stride]);
            *(u4v*)(Wrec + (size_t)R * 1024 + k0) = pack8(o);
        } else {
            int c = i - NX8 - NWI8 - NWR8;
            int dir = c / 3072, cc = c % 3072;
            bias[c] = (cc < 2048) ? (dir ? Binv : Bg)[cc]
                                  : (dir ? Bninvi : Bni)[cc - 2048];
        }
    }
}

// =====================================================================
// gemm_in: G[s*32+b][n] = bf16( x[b,s,:] @ Win[:,n] + bias[n] )
// =====================================================================
#define GLL16(gp, lp) __builtin_amdgcn_global_load_lds( \
    (const __attribute__((address_space(1))) void*)(gp), \
    (__attribute__((address_space(3))) void*)(lp), 16, 0, 0)

__global__ __launch_bounds__(256, 2) void gemm_in(
    const unsigned short* __restrict__ xb,
    const unsigned short* __restrict__ WinT,
    const float* __restrict__ bias,
    unsigned short* __restrict__ G)
{
    __shared__ char smem[32768];
    char* As = smem;
    char* Bs = smem + 16384;
    const int tid = threadIdx.x, lane = tid & 63, wid = tid >> 6;
    int wg = blockIdx.x;
    int swz = (wg & 7) * 1536 + (wg >> 3);   // 12288 = 8*1536, bijective XCD swizzle
    const int m0 = (swz & 255) * 128, n0 = (swz >> 8) * 128;
    const int l15 = lane & 15, hi = lane >> 4;
    const int mw = (wid & 1) * 64, nw = (wid >> 1) * 64;

    f4v acc[4][4] = {};

    const char* xrow = (const char*)xb;    // row stride 1024 B
    const char* wrow = (const char*)WinT;  // row stride 1024 B

    for (int kt = 0; kt < 8; ++kt) {
        const int kb0 = kt * 128;
#pragma unroll
        for (int r = 0; r < 4; ++r) {
            int q = wid * 4 + r;
            int o = q * 1024 + lane * 16;
            int row = o >> 7;
            int kbs = (o ^ ((row & 7) << 4)) & 127;   // inverse-swizzled source
            GLL16(xrow + (size_t)(m0 + row) * 1024 + kb0 + kbs, As + q * 1024);
            GLL16(wrow + (size_t)(n0 + row) * 1024 + kb0 + kbs, Bs + q * 1024);
        }
        __syncthreads();
#pragma unroll
        for (int kc = 0; kc < 2; ++kc) {
            s8v a[4], b[4];
#pragma unroll
            for (int mt = 0; mt < 4; ++mt) {
                int row = mw + mt * 16 + l15;
                int off = (row << 7) + kc * 64 + hi * 16;
                a[mt] = *(const s8v*)(As + (off ^ ((row & 7) << 4)));
            }
#pragma unroll
            for (int nt = 0; nt < 4; ++nt) {
                int row = nw + nt * 16 + l15;
                int off = (row << 7) + kc * 64 + hi * 16;
                b[nt] = *(const s8v*)(Bs + (off ^ ((row & 7) << 4)));
            }
#pragma unroll
            for (int mt = 0; mt < 4; ++mt)
#pragma unroll
                for (int nt = 0; nt < 4; ++nt)
                    acc[mt][nt] = __builtin_amdgcn_mfma_f32_16x16x32_bf16(
                        a[mt], b[nt], acc[mt][nt], 0, 0, 0);
        }
        __syncthreads();
    }
#pragma unroll
    for (int mt = 0; mt < 4; ++mt) {
#pragma unroll
        for (int rg = 0; rg < 4; ++rg) {
            int m = m0 + mw + mt * 16 + hi * 4 + rg;
            int bi = m >> 10, si = m & 1023;
            size_t gbase = (size_t)(si * 32 + bi) * NCOL;
#pragma unroll
            for (int nt = 0; nt < 4; ++nt) {
                int n = n0 + nw + nt * 16 + l15;
                G[gbase + n] = f2bf(acc[mt][nt][rg] + bias[n]);
            }
        }
    }
}

// =====================================================================
// gru_rec: persistent bidirectional GRU recurrence. 256 blocks (1/CU).
// block = (dir, 16-batch group, 16 hidden cols). Weights resident in LDS.
// Cross-block h exchange: write-through (sc0 sc1) stores + LLC-direct loads;
// barrier: per-block flag words, 4 independent 64-block groups, no fences.
// =====================================================================
__global__ __launch_bounds__(256, 1) void gru_rec(
    const unsigned short* __restrict__ G,     // [1024][32][6144]
    const unsigned short* __restrict__ Wrec,  // [2][3072][1024]
    const float* __restrict__ Bnh,
    const float* __restrict__ Bninvh,
    unsigned short* __restrict__ hbuf,        // [2][2][32][1024] bf16
    float* __restrict__ out,                  // [32][1024][2048] + ht [32][2048]
    unsigned int* __restrict__ flags)         // [4][64]
{
    extern __shared__ char smem[];
    char* wl = smem;                       // 96 KiB: [48 cols][1024 k] bf16, XOR-swizzled
    float* pl = (float*)(smem + 98304);    // partial sums [4 waves][3 panels][16][17]

    const int tid = threadIdx.x, lane = tid & 63, wid = tid >> 6;
    const int bid = blockIdx.x;
    const int dir = bid >> 7, bg = (bid >> 6) & 1, jg = bid & 63;
    const int jbase = jg * 16, bb = bg * 16;
    const int l15 = lane & 15, hi = lane >> 4;
    unsigned int* gflags = flags + (bid >> 6) * 64;   // this block's sync group

    // ---- one-time: load 3 weight panels (r,z,n) x [1024][16] into LDS ----
    {
        const char* wsrc = (const char*)Wrec;
        for (int q = 0; q < 24; ++q) {
            int o = (q * 256 + tid) * 16;
            int c = o >> 11;                               // 0..47
            int kb = (o ^ ((c & 7) << 4)) & 2047;          // inverse swizzle
            int n = dir * 3072 + (c >> 4) * 1024 + jbase + (c & 15);
            *(u4v*)(wl + o) = *(const u4v*)(wsrc + (size_t)n * 2048 + kb);
        }
    }
    const int b_l = tid >> 4, j_l = tid & 15;
    const float bnh = (dir ? Bninvh : Bnh)[jbase + j_l];
    __syncthreads();

    const int ks2 = wid * 512;   // this wave's K-slice byte offset (256 elems)
    float h_old = 0.0f;
    unsigned int* hbuf32 = (unsigned int*)hbuf;

    // prefetch G row for step 0 (normal cached loads; G is immutable)
    int g0 = dir ? 1023 : 0;
    const unsigned short* gp =
        G + ((size_t)(g0 * 32 + bb + b_l) * NCOL + dir * 3072 + jbase + j_l);
    unsigned short gr = gp[0], gz = gp[1024], gn = gp[2048];

    for (int s = 0; s < 1024; ++s) {
        float rsum = 0.f, zsum = 0.f, nsum = 0.f;
        if (s > 0) {
            const int rbuf = (s & 1) ^ 1;
            const char* hrow = (const char*)hbuf +
                ((size_t)((dir * 2 + rbuf) * 32 + bb + l15)) * 2048 + ks2 + hi * 16;
            u4v u[8];
            load_hrow(hrow, u[0], u[1], u[2], u[3], u[4], u[5], u[6], u[7]);
            f4v acc[3] = {};
#pragma unroll
            for (int p = 0; p < 3; ++p) {
                int c = p * 16 + l15;
                int cbase = c << 11;
                int sw = (c & 7) << 4;
#pragma unroll
                for (int kc = 0; kc < 8; ++kc) {
                    int off = cbase + ks2 + kc * 64 + hi * 16;
                    s8v bf = *(const s8v*)(wl + (off ^ sw));
                    acc[p] = __builtin_amdgcn_mfma_f32_16x16x32_bf16(
                        __builtin_bit_cast(s8v, u[kc]), bf, acc[p], 0, 0, 0);
                }
            }
#pragma unroll
            for (int p = 0; p < 3; ++p)
#pragma unroll
                for (int rg = 0; rg < 4; ++rg)
                    pl[((wid * 3 + p) * 16 + hi * 4 + rg) * 17 + l15] = acc[p][rg];
        }
        __syncthreads();
        if (s > 0) {
#pragma unroll
            for (int w = 0; w < 4; ++w) {
                rsum += pl[((w * 3 + 0) * 16 + b_l) * 17 + j_l];
                zsum += pl[((w * 3 + 1) * 16 + b_l) * 17 + j_l];
                nsum += pl[((w * 3 + 2) * 16 + b_l) * 17 + j_l];
            }
        }
        float rv = sigm(rsum + bf2f(gr));
        float zv = sigm(zsum + bf2f(gz));
        float nv = tanh_fast(bf2f(gn) + rv * (nsum + bnh));
        float hn = (1.0f - zv) * nv + zv * h_old;
        h_old = hn;

        // stores: h tile (write-through, paired u32), out (nontemporal)
        if (s < 1023) {
            unsigned short hb = f2bf(hn);
            unsigned int other = (unsigned int)(unsigned short)__shfl_xor((int)hb, 1);
            if (!(tid & 1)) {
                int row = (dir * 2 + (s & 1)) * 32 + bb + b_l;
                store_wt(hbuf32 + row * 512 + ((jbase + j_l) >> 1),
                         (unsigned)hb | (other << 16));
            }
        }
        const int s_out = dir ? (1023 - s) : s;
        __builtin_nontemporal_store(hn,
            &out[((size_t)(bb + b_l) * SS + s_out) * 2048 + dir * 1024 + jbase + j_l]);
        if (s == 1023)
            __builtin_nontemporal_store(hn,
                &out[(size_t)BB * SS * 2048 + (size_t)(bb + b_l) * 2048 +
                     dir * 1024 + jbase + j_l]);

        if (s < 1023) {
            // prefetch next step's G (immutable, normal cached loads)
            int g2 = dir ? (1022 - s) : (s + 1);
            const unsigned short* gp2 =
                G + ((size_t)(g2 * 32 + bb + b_l) * NCOL + dir * 3072 + jbase + j_l);
            gr = gp2[0]; gz = gp2[1024]; gn = gp2[2048];

            __syncthreads();   // drains all waves' stores to L2 (vmcnt(0) pre-barrier)
            if (tid == 0) {
                // release: wbl2 (cheap — L2 nearly clean) + sc0sc1 flag store.
                __hip_atomic_store(&gflags[bid & 63], (unsigned)(s + 1),
                                   __ATOMIC_RELEASE, __HIP_MEMORY_SCOPE_AGENT);
            }
            // all waves poll the 64 group flags (lane i <-> flag i)
            const unsigned tgt = (unsigned)(s + 1);
            unsigned v;
            do {
                v = __hip_atomic_load(&gflags[lane], __ATOMIC_RELAXED,
                                      __HIP_MEMORY_SCOPE_AGENT);
            } while (!__all(v >= tgt));
        }
    }
}

// =====================================================================
extern "C" void kernel_launch(void* const* d_in, const int* in_sizes, int n_in,
                              void* d_out, int out_size, void* d_ws, size_t ws_size,
                              hipStream_t stream)
{
    if (n_in < 15) return;
    const float* x      = (const float*)d_in[0];
    const float* Wi     = (const float*)d_in[1];
    const float* Wh     = (const float*)d_in[2];
    const float* Bg     = (const float*)d_in[3];
    const float* Wni    = (const float*)d_in[4];
    const float* Wnh    = (const float*)d_in[5];
    const float* Bni    = (const float*)d_in[6];
    const float* Bnh    = (const float*)d_in[7];
    const float* Winvi  = (const float*)d_in[8];
    const float* Winvh  = (const float*)d_in[9];
    const float* Binv   = (const float*)d_in[10];
    const float* Wninvi = (const float*)d_in[11];
    const float* Wninvh = (const float*)d_in[12];
    const float* Bninvi = (const float*)d_in[13];
    const float* Bninvh = (const float*)d_in[14];

    if (ws_size < WS_NEED) {
        hipMemsetAsync(d_out, 0, (size_t)out_size * 4, stream);
        return;
    }
    char* ws = (char*)d_ws;
    unsigned short* xb   = (unsigned short*)(ws + OFF_X);
    unsigned short* WinT = (unsigned short*)(ws + OFF_WINT);
    unsigned short* Wrec = (unsigned short*)(ws + OFF_WREC);
    float*          bias = (float*)(ws + OFF_BIAS);
    unsigned short* hbuf = (unsigned short*)(ws + OFF_H);
    unsigned int*   bar  = (unsigned int*)(ws + OFF_BAR);
    unsigned short* G    = (unsigned short*)(ws + OFF_G);

    hipMemsetAsync(ws + OFF_BAR, 0, SZ_BAR, stream);

    prep_kernel<<<4096, 256, 0, stream>>>(
        x, Wi, Wni, Winvi, Wninvi, Wh, Wnh, Winvh, Wninvh,
        Bg, Bni, Binv, Bninvi, xb, WinT, Wrec, bias);

    gemm_in<<<12288, 256, 0, stream>>>(xb, WinT, bias, G);

    const int smem_c = 98304 + 12 * 16 * 17 * 4;   // 111,360 B
    hipFuncSetAttribute(reinterpret_cast<const void*>(&gru_rec),
                        hipFuncAttributeMaxDynamicSharedMemorySize, smem_c);
    gru_rec<<<256, 256, smem_c, stream>>>(
        G, Wrec, Bnh, Bninvh, hbuf, (float*)d_out, bar);
}

// Round 3
// 7677.799 us; speedup vs baseline: 4.0309x; 1.9125x over previous
//
#include <hip/hip_runtime.h>
#include <cstdint>
#include <cstddef>

typedef __attribute__((ext_vector_type(8))) short s8v;          // 8 bf16
typedef __attribute__((ext_vector_type(4))) float f4v;
typedef __attribute__((ext_vector_type(4))) unsigned int u4v;

#define DEVFN __device__ __forceinline__

DEVFN unsigned short f2bf(float f) {
    unsigned int u = __builtin_bit_cast(unsigned int, f);
    return (unsigned short)((u + 0x7FFFu + ((u >> 16) & 1u)) >> 16);
}
DEVFN float bf2f(unsigned short h) {
    unsigned int u = ((unsigned int)h) << 16;
    return __builtin_bit_cast(float, u);
}
DEVFN float sigm(float x) { return 1.0f / (1.0f + __expf(-x)); }
DEVFN float tanh_fast(float x) { float e = __expf(2.0f * x); return 1.0f - 2.0f / (e + 1.0f); }

DEVFN u4v pack8(const unsigned short o[8]) {
    u4v v;
    v[0] = (unsigned)o[0] | ((unsigned)o[1] << 16);
    v[1] = (unsigned)o[2] | ((unsigned)o[3] << 16);
    v[2] = (unsigned)o[4] | ((unsigned)o[5] << 16);
    v[3] = (unsigned)o[6] | ((unsigned)o[7] << 16);
    return v;
}

// device-scope (LLC) write-through store — visible across XCDs, no fence.
DEVFN void store_wt(unsigned int* p, unsigned int v) {
    asm volatile("global_store_dword %0, %1, off sc0 sc1"
                 :: "v"(p), "v"(v) : "memory");
}
// LLC-direct flag read (bypasses stale L1/L2).
DEVFN unsigned load_flag(const unsigned int* p) {
    unsigned v;
    asm volatile("global_load_dword %0, %1, off sc0 sc1\n\t"
                 "s_waitcnt vmcnt(0)"
                 : "=v"(v) : "v"(p) : "memory");
    return v;
}
// 8x dwordx4 LLC-direct loads + drain (h row slice).
DEVFN void load_hrow(const void* p, u4v& a0, u4v& a1, u4v& a2, u4v& a3,
                     u4v& a4, u4v& a5, u4v& a6, u4v& a7) {
    asm volatile(
        "global_load_dwordx4 %0, %8, off sc0 sc1\n\t"
        "global_load_dwordx4 %1, %8, off offset:64 sc0 sc1\n\t"
        "global_load_dwordx4 %2, %8, off offset:128 sc0 sc1\n\t"
        "global_load_dwordx4 %3, %8, off offset:192 sc0 sc1\n\t"
        "global_load_dwordx4 %4, %8, off offset:256 sc0 sc1\n\t"
        "global_load_dwordx4 %5, %8, off offset:320 sc0 sc1\n\t"
        "global_load_dwordx4 %6, %8, off offset:384 sc0 sc1\n\t"
        "global_load_dwordx4 %7, %8, off offset:448 sc0 sc1\n\t"
        "s_waitcnt vmcnt(0)"
        : "=&v"(a0), "=&v"(a1), "=&v"(a2), "=&v"(a3),
          "=&v"(a4), "=&v"(a5), "=&v"(a6), "=&v"(a7)
        : "v"(p)
        : "memory");
}

// ---------------- geometry ----------------
constexpr int BB = 32, SS = 1024, II = 512, HH = 1024;
constexpr int NCOL = 6144;

constexpr size_t OFF_X    = 0;                       // bf16 x   [32768][512]
constexpr size_t SZ_X     = (size_t)BB * SS * II * 2;
constexpr size_t OFF_WINT = OFF_X + SZ_X;            // bf16 WinT [6144][512]
constexpr size_t SZ_WINT  = (size_t)NCOL * II * 2;
constexpr size_t OFF_WREC = OFF_WINT + SZ_WINT;      // bf16 Wrec [2][3072][1024]
constexpr size_t SZ_WREC  = (size_t)2 * 3072 * HH * 2;
constexpr size_t OFF_BIAS = OFF_WREC + SZ_WREC;      // f32 [6144]
constexpr size_t SZ_BIAS  = (size_t)NCOL * 4;
constexpr size_t OFF_H    = OFF_BIAS + SZ_BIAS;      // bf16 h ping-pong [2][2][32][1024]
constexpr size_t SZ_H     = (size_t)2 * 2 * BB * HH * 2;
constexpr size_t OFF_BAR  = OFF_H + SZ_H;            // flag words [4 groups][64]
constexpr size_t SZ_BAR   = 2048;
// G relayout: [s][dir][jg(64)][bg(2)][b16(16)][gate(3)][j(16)] bf16
constexpr size_t OFF_G    = OFF_BAR + SZ_BAR;
constexpr size_t SZ_G     = (size_t)SS * BB * NCOL * 2;
constexpr size_t WS_NEED  = OFF_G + SZ_G;            // ~455 MB

// =====================================================================
// prep
// =====================================================================
__global__ void prep_kernel(
    const float* __restrict__ x,
    const float* __restrict__ Wi, const float* __restrict__ Wni,
    const float* __restrict__ Winvi, const float* __restrict__ Wninvi,
    const float* __restrict__ Wh, const float* __restrict__ Wnh,
    const float* __restrict__ Winvh, const float* __restrict__ Wninvh,
    const float* __restrict__ Bg, const float* __restrict__ Bni,
    const float* __restrict__ Binv, const float* __restrict__ Bninvi,
    unsigned short* __restrict__ xb, unsigned short* __restrict__ WinT,
    unsigned short* __restrict__ Wrec, float* __restrict__ bias)
{
    constexpr int NX8  = (BB * SS * II) / 8;
    constexpr int NWI8 = (NCOL * II) / 8;
    constexpr int NWR8 = (2 * 3072 * HH) / 8;
    constexpr int TOT  = NX8 + NWI8 + NWR8 + NCOL;
    for (int i = blockIdx.x * blockDim.x + threadIdx.x; i < TOT;
         i += gridDim.x * blockDim.x) {
        if (i < NX8) {
            const float* sp = x + (size_t)i * 8;
            unsigned short o[8];
#pragma unroll
            for (int j = 0; j < 8; ++j) o[j] = f2bf(sp[j]);
            *(u4v*)(xb + (size_t)i * 8) = pack8(o);
        } else if (i < NX8 + NWI8) {
            int u = i - NX8;
            int n = u >> 6, k0 = (u & 63) * 8;
            const float* src; int stride;
            if (n < 2048)      { src = Wi + n;            stride = 2048; }
            else if (n < 3072) { src = Wni + (n - 2048);  stride = 1024; }
            else if (n < 5120) { src = Winvi + (n - 3072); stride = 2048; }
            else               { src = Wninvi + (n - 5120); stride = 1024; }
            unsigned short o[8];
#pragma unroll
            for (int j = 0; j < 8; ++j) o[j] = f2bf(src[(size_t)(k0 + j) * stride]);
            *(u4v*)(WinT + (size_t)n * 512 + k0) = pack8(o);
        } else if (i < NX8 + NWI8 + NWR8) {
            int u = i - NX8 - NWI8;
            int R = u >> 7, k0 = (u & 127) * 8;
            int dir = R / 3072, n = R % 3072;
            const float* src; int stride;
            if (n < 2048) { src = (dir ? Winvh : Wh) + n;          stride = 2048; }
            else          { src = (dir ? Wninvh : Wnh) + (n - 2048); stride = 1024; }
            unsigned short o[8];
#pragma unroll
            for (int j = 0; j < 8; ++j) o[j] = f2bf(src[(size_t)(k0 + j) * stride]);
            *(u4v*)(Wrec + (size_t)R * 1024 + k0) = pack8(o);
        } else {
            int c = i - NX8 - NWI8 - NWR8;
            int dir = c / 3072, cc = c % 3072;
            bias[c] = (cc < 2048) ? (dir ? Binv : Bg)[cc]
                                  : (dir ? Bninvi : Bni)[cc - 2048];
        }
    }
}

// =====================================================================
// gemm_in
// =====================================================================
#define GLL16(gp, lp) __builtin_amdgcn_global_load_lds( \
    (const __attribute__((address_space(1))) void*)(gp), \
    (__attribute__((address_space(3))) void*)(lp), 16, 0, 0)

__global__ __launch_bounds__(256, 2) void gemm_in(
    const unsigned short* __restrict__ xb,
    const unsigned short* __restrict__ WinT,
    const float* __restrict__ bias,
    unsigned short* __restrict__ G)
{
    __shared__ char smem[32768];
    char* As = smem;
    char* Bs = smem + 16384;
    const int tid = threadIdx.x, lane = tid & 63, wid = tid >> 6;
    int wg = blockIdx.x;
    int swz = (wg & 7) * 1536 + (wg >> 3);
    const int m0 = (swz & 255) * 128, n0 = (swz >> 8) * 128;
    const int l15 = lane & 15, hi = lane >> 4;
    const int mw = (wid & 1) * 64, nw = (wid >> 1) * 64;

    f4v acc[4][4] = {};

    const char* xrow = (const char*)xb;
    const char* wrow = (const char*)WinT;

    for (int kt = 0; kt < 8; ++kt) {
        const int kb0 = kt * 128;
#pragma unroll
        for (int r = 0; r < 4; ++r) {
            int q = wid * 4 + r;
            int o = q * 1024 + lane * 16;
            int row = o >> 7;
            int kbs = (o ^ ((row & 7) << 4)) & 127;
            GLL16(xrow + (size_t)(m0 + row) * 1024 + kb0 + kbs, As + q * 1024);
            GLL16(wrow + (size_t)(n0 + row) * 1024 + kb0 + kbs, Bs + q * 1024);
        }
        __syncthreads();
#pragma unroll
        for (int kc = 0; kc < 2; ++kc) {
            s8v a[4], b[4];
#pragma unroll
            for (int mt = 0; mt < 4; ++mt) {
                int row = mw + mt * 16 + l15;
                int off = (row << 7) + kc * 64 + hi * 16;
                a[mt] = *(const s8v*)(As + (off ^ ((row & 7) << 4)));
            }
#pragma unroll
            for (int nt = 0; nt < 4; ++nt) {
                int row = nw + nt * 16 + l15;
                int off = (row << 7) + kc * 64 + hi * 16;
                b[nt] = *(const s8v*)(Bs + (off ^ ((row & 7) << 4)));
            }
#pragma unroll
            for (int mt = 0; mt < 4; ++mt)
#pragma unroll
                for (int nt = 0; nt < 4; ++nt)
                    acc[mt][nt] = __builtin_amdgcn_mfma_f32_16x16x32_bf16(
                        a[mt], b[nt], acc[mt][nt], 0, 0, 0);
        }
        __syncthreads();
    }
    // epilogue: +bias, scatter into block-contiguous G layout
    // G[s][dir][jg][bg][b16][gate][j]
#pragma unroll
    for (int mt = 0; mt < 4; ++mt) {
#pragma unroll
        for (int rg = 0; rg < 4; ++rg) {
            int m = m0 + mw + mt * 16 + hi * 4 + rg;
            int bi = m >> 10, si = m & 1023;
            int bg = bi >> 4, b16 = bi & 15;
#pragma unroll
            for (int nt = 0; nt < 4; ++nt) {
                int n = n0 + nw + nt * 16 + l15;
                int dir = (n >= 3072);
                int rem = n - dir * 3072;
                int gate = rem >> 10, col = rem & 1023;
                int jg = col >> 4, j = col & 15;
                size_t idx = (((((size_t)si * 2 + dir) * 64 + jg) * 2 + bg) * 16
                              + b16) * 48 + gate * 16 + j;
                G[idx] = f2bf(acc[mt][nt][rg] + bias[n]);
            }
        }
    }
}

// =====================================================================
// gru_rec: persistent bidirectional GRU recurrence, 256 blocks (1/CU).
// Sync per step: sc0sc1 write-through h + vmcnt(0) + plain sc0sc1 flag store,
// pollers use sc0sc1 flag loads. NO cache-wide maintenance ops anywhere.
// =====================================================================
__global__ __launch_bounds__(256, 1) void gru_rec(
    const unsigned short* __restrict__ G,     // [s][dir][jg][bg][b16][gate][j]
    const unsigned short* __restrict__ Wrec,  // [2][3072][1024]
    const float* __restrict__ Bnh,
    const float* __restrict__ Bninvh,
    unsigned short* __restrict__ hbuf,        // [2][2][32][1024] bf16
    float* __restrict__ out,                  // [32][1024][2048] + ht [32][2048]
    unsigned int* __restrict__ flags)         // [4][64]
{
    extern __shared__ char smem[];
    char* wl = smem;                       // 96 KiB weights, XOR-swizzled
    float* pl = (float*)(smem + 98304);    // partials [4 waves][3 gates][16][17]

    const int tid = threadIdx.x, lane = tid & 63, wid = tid >> 6;
    const int bid = blockIdx.x;
    const int dir = bid >> 7, bg = (bid >> 6) & 1, jg = bid & 63;
    const int jbase = jg * 16, bb = bg * 16;
    const int l15 = lane & 15, hi = lane >> 4;
    unsigned int* gflags = flags + (bid >> 6) * 64;

    // ---- one-time: stage 3 weight panels [1024][16] into LDS ----
    {
        const char* wsrc = (const char*)Wrec;
        for (int q = 0; q < 24; ++q) {
            int o = (q * 256 + tid) * 16;
            int c = o >> 11;
            int kb = (o ^ ((c & 7) << 4)) & 2047;
            int n = dir * 3072 + (c >> 4) * 1024 + jbase + (c & 15);
            *(u4v*)(wl + o) = *(const u4v*)(wsrc + (size_t)n * 2048 + kb);
        }
    }
    const int b_l = tid >> 4, j_l = tid & 15;
    const float bnh = (dir ? Bninvh : Bnh)[jbase + j_l];
    __syncthreads();

    const int ks2 = wid * 512;
    float h_old = 0.0f;
    unsigned int* hbuf32 = (unsigned int*)hbuf;

    // per-block G chunk base helper: 768 elements per (s,dir,jg,bg)
    const size_t gstride = (size_t)2 * 64 * 2 * 768;   // per-s stride = 196608
    const unsigned short* gchunk0 =
        G + (((size_t)dir * 64 + jg) * 2 + bg) * 768 + b_l * 48 + j_l;

    // prefetch G for step 0
    {
        int g0 = dir ? 1023 : 0;
        const unsigned short* gp = gchunk0 + (size_t)g0 * gstride;
        // issued early; consumed below
        asm volatile("" ::: "memory");
        // loads
        // (normal cached loads; G is immutable within this kernel)
        // stored into gr/gz/gn
        // fallthrough
        // note: separate statement to keep them adjacent
        (void)gp;
    }
    int gfirst = dir ? 1023 : 0;
    const unsigned short* gp0 = gchunk0 + (size_t)gfirst * gstride;
    unsigned short gr = gp0[0], gz = gp0[16], gn = gp0[32];

    for (int s = 0; s < 1024; ++s) {
        float rsum = 0.f, zsum = 0.f, nsum = 0.f;
        if (s > 0) {
            const int rbuf = (s & 1) ^ 1;
            const char* hrow = (const char*)hbuf +
                ((size_t)((dir * 2 + rbuf) * 32 + bb + l15)) * 2048 + ks2 + hi * 16;
            u4v u[8];
            load_hrow(hrow, u[0], u[1], u[2], u[3], u[4], u[5], u[6], u[7]);
            f4v acc[3] = {};
#pragma unroll
            for (int p = 0; p < 3; ++p) {
                int c = p * 16 + l15;
                int cbase = c << 11;
                int sw = (c & 7) << 4;
#pragma unroll
                for (int kc = 0; kc < 8; ++kc) {
                    int off = cbase + ks2 + kc * 64 + hi * 16;
                    s8v bf = *(const s8v*)(wl + (off ^ sw));
                    acc[p] = __builtin_amdgcn_mfma_f32_16x16x32_bf16(
                        __builtin_bit_cast(s8v, u[kc]), bf, acc[p], 0, 0, 0);
                }
            }
#pragma unroll
            for (int p = 0; p < 3; ++p)
#pragma unroll
                for (int rg = 0; rg < 4; ++rg)
                    pl[((wid * 3 + p) * 16 + hi * 4 + rg) * 17 + l15] = acc[p][rg];
        }
        __syncthreads();
        if (s > 0) {
#pragma unroll
            for (int w = 0; w < 4; ++w) {
                rsum += pl[((w * 3 + 0) * 16 + b_l) * 17 + j_l];
                zsum += pl[((w * 3 + 1) * 16 + b_l) * 17 + j_l];
                nsum += pl[((w * 3 + 2) * 16 + b_l) * 17 + j_l];
            }
        }

        // issue next-step G prefetch early (latency hides under gate math)
        unsigned short gr2 = 0, gz2 = 0, gn2 = 0;
        if (s < 1023) {
            int g2 = dir ? (1022 - s) : (s + 1);
            const unsigned short* gp2 = gchunk0 + (size_t)g2 * gstride;
            gr2 = gp2[0]; gz2 = gp2[16]; gn2 = gp2[32];
        }

        float rv = sigm(rsum + bf2f(gr));
        float zv = sigm(zsum + bf2f(gz));
        float nv = tanh_fast(bf2f(gn) + rv * (nsum + bnh));
        float hn = (1.0f - zv) * nv + zv * h_old;
        h_old = hn;
        gr = gr2; gz = gz2; gn = gn2;

        if (s < 1023) {
            unsigned short hb = f2bf(hn);
            unsigned int other = (unsigned int)(unsigned short)__shfl_xor((int)hb, 1);
            if (!(tid & 1)) {
                int row = (dir * 2 + (s & 1)) * 32 + bb + b_l;
                store_wt(hbuf32 + row * 512 + ((jbase + j_l) >> 1),
                         (unsigned)hb | (other << 16));
            }
        }
        const int s_out = dir ? (1023 - s) : s;
        __builtin_nontemporal_store(hn,
            &out[((size_t)(bb + b_l) * SS + s_out) * 2048 + dir * 1024 + jbase + j_l]);
        if (s == 1023)
            __builtin_nontemporal_store(hn,
                &out[(size_t)BB * SS * 2048 + (size_t)(bb + b_l) * 2048 +
                     dir * 1024 + jbase + j_l]);

        if (s < 1023) {
            // drain h stores to LLC, then block-wide rendezvous, then flag.
            asm volatile("s_waitcnt vmcnt(0)" ::: "memory");
            __syncthreads();
            if (tid == 0)
                store_wt(&gflags[bid & 63], (unsigned)(s + 1));
            const unsigned tgt = (unsigned)(s + 1);
            unsigned v;
            do {
                v = load_flag(&gflags[lane]);
            } while (!__all(v >= tgt));
        }
    }
}

// =====================================================================
extern "C" void kernel_launch(void* const* d_in, const int* in_sizes, int n_in,
                              void* d_out, int out_size, void* d_ws, size_t ws_size,
                              hipStream_t stream)
{
    if (n_in < 15) return;
    const float* x      = (const float*)d_in[0];
    const float* Wi     = (const float*)d_in[1];
    const float* Wh     = (const float*)d_in[2];
    const float* Bg     = (const float*)d_in[3];
    const float* Wni    = (const float*)d_in[4];
    const float* Wnh    = (const float*)d_in[5];
    const float* Bni    = (const float*)d_in[6];
    const float* Bnh    = (const float*)d_in[7];
    const float* Winvi  = (const float*)d_in[8];
    const float* Winvh  = (const float*)d_in[9];
    const float* Binv   = (const float*)d_in[10];
    const float* Wninvi = (const float*)d_in[11];
    const float* Wninvh = (const float*)d_in[12];
    const float* Bninvi = (const float*)d_in[13];
    const float* Bninvh = (const float*)d_in[14];

    if (ws_size < WS_NEED) {
        hipMemsetAsync(d_out, 0, (size_t)out_size * 4, stream);
        return;
    }
    char* ws = (char*)d_ws;
    unsigned short* xb   = (unsigned short*)(ws + OFF_X);
    unsigned short* WinT = (unsigned short*)(ws + OFF_WINT);
    unsigned short* Wrec = (unsigned short*)(ws + OFF_WREC);
    float*          bias = (float*)(ws + OFF_BIAS);
    unsigned short* hbuf = (unsigned short*)(ws + OFF_H);
    unsigned int*   bar  = (unsigned int*)(ws + OFF_BAR);
    unsigned short* G    = (unsigned short*)(ws + OFF_G);

    hipMemsetAsync(ws + OFF_BAR, 0, SZ_BAR, stream);

    prep_kernel<<<4096, 256, 0, stream>>>(
        x, Wi, Wni, Winvi, Wninvi, Wh, Wnh, Winvh, Wninvh,
        Bg, Bni, Binv, Bninvi, xb, WinT, Wrec, bias);

    gemm_in<<<12288, 256, 0, stream>>>(xb, WinT, bias, G);

    const int smem_c = 98304 + 12 * 16 * 17 * 4;   // 111,360 B
    hipFuncSetAttribute(reinterpret_cast<const void*>(&gru_rec),
                        hipFuncAttributeMaxDynamicSharedMemorySize, smem_c);
    gru_rec<<<256, 256, smem_c, stream>>>(
        G, Wrec, Bnh, Bninvh, hbuf, (float*)d_out, bar);
}

// Round 4
// 6554.196 us; speedup vs baseline: 4.7219x; 1.1714x over previous
//
#include <hip/hip_runtime.h>
#include <cstdint>
#include <cstddef>

typedef __attribute__((ext_vector_type(8))) short s8v;          // 8 bf16
typedef __attribute__((ext_vector_type(4))) float f4v;
typedef __attribute__((ext_vector_type(4))) unsigned int u4v;

#define DEVFN __device__ __forceinline__

DEVFN unsigned short f2bf(float f) {
    unsigned int u = __builtin_bit_cast(unsigned int, f);
    return (unsigned short)((u + 0x7FFFu + ((u >> 16) & 1u)) >> 16);
}
DEVFN float bf2f(unsigned short h) {
    unsigned int u = ((unsigned int)h) << 16;
    return __builtin_bit_cast(float, u);
}
DEVFN float sigm(float x) { return 1.0f / (1.0f + __expf(-x)); }
DEVFN float tanh_fast(float x) { float e = __expf(2.0f * x); return 1.0f - 2.0f / (e + 1.0f); }

DEVFN u4v pack8(const unsigned short o[8]) {
    u4v v;
    v[0] = (unsigned)o[0] | ((unsigned)o[1] << 16);
    v[1] = (unsigned)o[2] | ((unsigned)o[3] << 16);
    v[2] = (unsigned)o[4] | ((unsigned)o[5] << 16);
    v[3] = (unsigned)o[6] | ((unsigned)o[7] << 16);
    return v;
}

// device-scope (LLC) write-through store — visible across XCDs, no fence.
DEVFN void store_wt(unsigned int* p, unsigned int v) {
    asm volatile("global_store_dword %0, %1, off sc0 sc1"
                 :: "v"(p), "v"(v) : "memory");
}
// LLC-direct flag read (bypasses stale L1/L2).
DEVFN unsigned poll_load(const unsigned int* p) {
    unsigned v;
    asm volatile("global_load_dword %0, %1, off sc0 sc1\n\t"
                 "s_waitcnt vmcnt(0)"
                 : "=v"(v) : "v"(p) : "memory");
    return v;
}
// 8x dwordx4 LLC-direct tile gather + drain. Offsets 0..3072 on two bases
// (13-bit signed imm caps at 4095).
DEVFN void gather_h(const void* p0, const void* p1,
                    u4v& a0, u4v& a1, u4v& a2, u4v& a3,
                    u4v& a4, u4v& a5, u4v& a6, u4v& a7) {
    asm volatile(
        "global_load_dwordx4 %0, %8, off sc0 sc1\n\t"
        "global_load_dwordx4 %1, %8, off offset:1024 sc0 sc1\n\t"
        "global_load_dwordx4 %2, %8, off offset:2048 sc0 sc1\n\t"
        "global_load_dwordx4 %3, %8, off offset:3072 sc0 sc1\n\t"
        "global_load_dwordx4 %4, %9, off sc0 sc1\n\t"
        "global_load_dwordx4 %5, %9, off offset:1024 sc0 sc1\n\t"
        "global_load_dwordx4 %6, %9, off offset:2048 sc0 sc1\n\t"
        "global_load_dwordx4 %7, %9, off offset:3072 sc0 sc1\n\t"
        "s_waitcnt vmcnt(0)"
        : "=&v"(a0), "=&v"(a1), "=&v"(a2), "=&v"(a3),
          "=&v"(a4), "=&v"(a5), "=&v"(a6), "=&v"(a7)
        : "v"(p0), "v"(p1)
        : "memory");
}

// ---------------- geometry ----------------
constexpr int BB = 32, SS = 1024, II = 512, HH = 1024;
constexpr int NCOL = 6144;

constexpr size_t OFF_X    = 0;                       // bf16 x   [32768][512]
constexpr size_t SZ_X     = (size_t)BB * SS * II * 2;
constexpr size_t OFF_WINT = OFF_X + SZ_X;            // bf16 WinT [6144][512]
constexpr size_t SZ_WINT  = (size_t)NCOL * II * 2;
constexpr size_t OFF_WREC = OFF_WINT + SZ_WINT;      // bf16 Wrec [2][3072][1024]
constexpr size_t SZ_WREC  = (size_t)2 * 3072 * HH * 2;
constexpr size_t OFF_BIAS = OFF_WREC + SZ_WREC;      // f32 [6144]
constexpr size_t SZ_BIAS  = (size_t)NCOL * 4;
// h tiles: [dir][buf][bg][jg(64)][b16(16)][j16(16)] bf16 — 512 B per tile
constexpr size_t OFF_H    = OFF_BIAS + SZ_BIAS;
constexpr size_t SZ_H     = (size_t)2 * 2 * 2 * 64 * 512;
constexpr size_t OFF_BAR  = OFF_H + SZ_H;            // flags [4 groups][64 jg][4 wave]
constexpr size_t SZ_BAR   = 4096;
// G layout: [s][dir][jg(64)][bg(2)][b16(16)][gate(3)][j(16)] bf16
constexpr size_t OFF_G    = OFF_BAR + SZ_BAR;
constexpr size_t SZ_G     = (size_t)SS * BB * NCOL * 2;
constexpr size_t WS_NEED  = OFF_G + SZ_G;            // ~455 MB

// =====================================================================
// prep
// =====================================================================
__global__ void prep_kernel(
    const float* __restrict__ x,
    const float* __restrict__ Wi, const float* __restrict__ Wni,
    const float* __restrict__ Winvi, const float* __restrict__ Wninvi,
    const float* __restrict__ Wh, const float* __restrict__ Wnh,
    const float* __restrict__ Winvh, const float* __restrict__ Wninvh,
    const float* __restrict__ Bg, const float* __restrict__ Bni,
    const float* __restrict__ Binv, const float* __restrict__ Bninvi,
    unsigned short* __restrict__ xb, unsigned short* __restrict__ WinT,
    unsigned short* __restrict__ Wrec, float* __restrict__ bias)
{
    constexpr int NX8  = (BB * SS * II) / 8;
    constexpr int NWI8 = (NCOL * II) / 8;
    constexpr int NWR8 = (2 * 3072 * HH) / 8;
    constexpr int TOT  = NX8 + NWI8 + NWR8 + NCOL;
    for (int i = blockIdx.x * blockDim.x + threadIdx.x; i < TOT;
         i += gridDim.x * blockDim.x) {
        if (i < NX8) {
            const float* sp = x + (size_t)i * 8;
            unsigned short o[8];
#pragma unroll
            for (int j = 0; j < 8; ++j) o[j] = f2bf(sp[j]);
            *(u4v*)(xb + (size_t)i * 8) = pack8(o);
        } else if (i < NX8 + NWI8) {
            int u = i - NX8;
            int n = u >> 6, k0 = (u & 63) * 8;
            const float* src; int stride;
            if (n < 2048)      { src = Wi + n;            stride = 2048; }
            else if (n < 3072) { src = Wni + (n - 2048);  stride = 1024; }
            else if (n < 5120) { src = Winvi + (n - 3072); stride = 2048; }
            else               { src = Wninvi + (n - 5120); stride = 1024; }
            unsigned short o[8];
#pragma unroll
            for (int j = 0; j < 8; ++j) o[j] = f2bf(src[(size_t)(k0 + j) * stride]);
            *(u4v*)(WinT + (size_t)n * 512 + k0) = pack8(o);
        } else if (i < NX8 + NWI8 + NWR8) {
            int u = i - NX8 - NWI8;
            int R = u >> 7, k0 = (u & 127) * 8;
            int dir = R / 3072, n = R % 3072;
            const float* src; int stride;
            if (n < 2048) { src = (dir ? Winvh : Wh) + n;          stride = 2048; }
            else          { src = (dir ? Wninvh : Wnh) + (n - 2048); stride = 1024; }
            unsigned short o[8];
#pragma unroll
            for (int j = 0; j < 8; ++j) o[j] = f2bf(src[(size_t)(k0 + j) * stride]);
            *(u4v*)(Wrec + (size_t)R * 1024 + k0) = pack8(o);
        } else {
            int c = i - NX8 - NWI8 - NWR8;
            int dir = c / 3072, cc = c % 3072;
            bias[c] = (cc < 2048) ? (dir ? Binv : Bg)[cc]
                                  : (dir ? Bninvi : Bni)[cc - 2048];
        }
    }
}

// =====================================================================
// gemm_in (unchanged from round 3)
// =====================================================================
#define GLL16(gp, lp) __builtin_amdgcn_global_load_lds( \
    (const __attribute__((address_space(1))) void*)(gp), \
    (__attribute__((address_space(3))) void*)(lp), 16, 0, 0)

__global__ __launch_bounds__(256, 2) void gemm_in(
    const unsigned short* __restrict__ xb,
    const unsigned short* __restrict__ WinT,
    const float* __restrict__ bias,
    unsigned short* __restrict__ G)
{
    __shared__ char smem[32768];
    char* As = smem;
    char* Bs = smem + 16384;
    const int tid = threadIdx.x, lane = tid & 63, wid = tid >> 6;
    int wg = blockIdx.x;
    int swz = (wg & 7) * 1536 + (wg >> 3);
    const int m0 = (swz & 255) * 128, n0 = (swz >> 8) * 128;
    const int l15 = lane & 15, hi = lane >> 4;
    const int mw = (wid & 1) * 64, nw = (wid >> 1) * 64;

    f4v acc[4][4] = {};

    const char* xrow = (const char*)xb;
    const char* wrow = (const char*)WinT;

    for (int kt = 0; kt < 8; ++kt) {
        const int kb0 = kt * 128;
#pragma unroll
        for (int r = 0; r < 4; ++r) {
            int q = wid * 4 + r;
            int o = q * 1024 + lane * 16;
            int row = o >> 7;
            int kbs = (o ^ ((row & 7) << 4)) & 127;
            GLL16(xrow + (size_t)(m0 + row) * 1024 + kb0 + kbs, As + q * 1024);
            GLL16(wrow + (size_t)(n0 + row) * 1024 + kb0 + kbs, Bs + q * 1024);
        }
        __syncthreads();
#pragma unroll
        for (int kc = 0; kc < 2; ++kc) {
            s8v a[4], b[4];
#pragma unroll
            for (int mt = 0; mt < 4; ++mt) {
                int row = mw + mt * 16 + l15;
                int off = (row << 7) + kc * 64 + hi * 16;
                a[mt] = *(const s8v*)(As + (off ^ ((row & 7) << 4)));
            }
#pragma unroll
            for (int nt = 0; nt < 4; ++nt) {
                int row = nw + nt * 16 + l15;
                int off = (row << 7) + kc * 64 + hi * 16;
                b[nt] = *(const s8v*)(Bs + (off ^ ((row & 7) << 4)));
            }
#pragma unroll
            for (int mt = 0; mt < 4; ++mt)
#pragma unroll
                for (int nt = 0; nt < 4; ++nt)
                    acc[mt][nt] = __builtin_amdgcn_mfma_f32_16x16x32_bf16(
                        a[mt], b[nt], acc[mt][nt], 0, 0, 0);
        }
        __syncthreads();
    }
    // epilogue: +bias, scatter into block-contiguous G layout
#pragma unroll
    for (int mt = 0; mt < 4; ++mt) {
#pragma unroll
        for (int rg = 0; rg < 4; ++rg) {
            int m = m0 + mw + mt * 16 + hi * 4 + rg;
            int bi = m >> 10, si = m & 1023;
            int bg = bi >> 4, b16 = bi & 15;
#pragma unroll
            for (int nt = 0; nt < 4; ++nt) {
                int n = n0 + nw + nt * 16 + l15;
                int dir = (n >= 3072);
                int rem = n - dir * 3072;
                int gate = rem >> 10, col = rem & 1023;
                int jg = col >> 4, j = col & 15;
                size_t idx = (((((size_t)si * 2 + dir) * 64 + jg) * 2 + bg) * 16
                              + b16) * 48 + gate * 16 + j;
                G[idx] = f2bf(acc[mt][nt][rg] + bias[n]);
            }
        }
    }
}

// =====================================================================
// gru_rec: persistent bidirectional GRU recurrence, 256 blocks (1/CU).
// Per-wave flags + wave-subset polling; contiguous 512B h tiles (full-line
// write-through); out via plain L2 stores; one __syncthreads per step.
// =====================================================================
__global__ __launch_bounds__(256, 1) void gru_rec(
    const unsigned short* __restrict__ G,     // [s][dir][jg][bg][b16][gate][j]
    const unsigned short* __restrict__ Wrec,  // [2][3072][1024]
    const float* __restrict__ Bnh,
    const float* __restrict__ Bninvh,
    unsigned short* __restrict__ hbuf,        // tiles [dir][buf][bg][jg][16][16]
    float* __restrict__ out,                  // [32][1024][2048] + ht [32][2048]
    unsigned int* __restrict__ flags)         // [4 groups][64 jg][4 wave]
{
    extern __shared__ char smem[];
    char* wl = smem;                       // 96 KiB weights, XOR-swizzled
    float* pl = (float*)(smem + 98304);    // partials x2 parity [4][3][16][17]
    constexpr int PLF = 4 * 3 * 16 * 17;   // floats per parity buffer

    const int tid = threadIdx.x, lane = tid & 63, wid = tid >> 6;
    const int bid = blockIdx.x;
    const int dir = bid >> 7, bg = (bid >> 6) & 1, jg = bid & 63;
    const int jbase = jg * 16, bb = bg * 16;
    const int l15 = lane & 15, hi = lane >> 4;
    unsigned int* fl = flags + ((dir * 2 + bg) << 8);   // group flag base

    // ---- one-time: stage 3 weight panels [1024][16] into LDS ----
    {
        const char* wsrc = (const char*)Wrec;
        for (int q = 0; q < 24; ++q) {
            int o = (q * 256 + tid) * 16;
            int c = o >> 11;
            int kb = (o ^ ((c & 7) << 4)) & 2047;
            int n = dir * 3072 + (c >> 4) * 1024 + jbase + (c & 15);
            *(u4v*)(wl + o) = *(const u4v*)(wsrc + (size_t)n * 2048 + kb);
        }
    }
    const int b_l = tid >> 4, j_l = tid & 15;
    const float bnh = (dir ? Bninvh : Bnh)[jbase + j_l];
    __syncthreads();

    float h_old = 0.0f;
    unsigned int* hbuf32 = (unsigned int*)hbuf;

    // per-block G chunk: 768 elements per (s,dir,jg,bg)
    const size_t gstride = (size_t)2 * 64 * 2 * 768;
    const unsigned short* gchunk0 =
        G + (((size_t)dir * 64 + jg) * 2 + bg) * 768 + b_l * 48 + j_l;

    int gfirst = dir ? 1023 : 0;
    const unsigned short* gp0 = gchunk0 + (size_t)gfirst * gstride;
    unsigned short gr = gp0[0], gz = gp0[16], gn = gp0[32];

    for (int s = 0; s < 1024; ++s) {
        const int par = s & 1;
        float* plc = pl + par * PLF;
        float rsum = 0.f, zsum = 0.f, nsum = 0.f;

        if (s > 0) {
            // ---- wave-subset poll: 16 producer blocks x 4 wave-flags ----
            const unsigned tgt = (unsigned)s;
            const unsigned int* fp = fl + wid * 64 + lane;
            unsigned v;
            do { v = poll_load(fp); } while (!__all(v >= tgt));

            // ---- gather h tiles (contiguous 512B per producer block) ----
            const int rbuf = par ^ 1;
            const char* hb = (const char*)hbuf +
                ((((size_t)(dir * 2 + rbuf) * 2 + bg) * 64)
                 + (size_t)(wid * 16 + (hi >> 1))) * 512
                + l15 * 32 + (hi & 1) * 16;
            u4v u[8];
            gather_h(hb, hb + 4096, u[0], u[1], u[2], u[3],
                     u[4], u[5], u[6], u[7]);

            f4v acc[3] = {};
#pragma unroll
            for (int p = 0; p < 3; ++p) {
                int c = p * 16 + l15;
                int cbase = c << 11;
                int sw = (c & 7) << 4;
#pragma unroll
                for (int kc = 0; kc < 8; ++kc) {
                    int off = cbase + (wid << 9) + kc * 64 + hi * 16;
                    s8v bf = *(const s8v*)(wl + (off ^ sw));
                    acc[p] = __builtin_amdgcn_mfma_f32_16x16x32_bf16(
                        __builtin_bit_cast(s8v, u[kc]), bf, acc[p], 0, 0, 0);
                }
            }
#pragma unroll
            for (int p = 0; p < 3; ++p)
#pragma unroll
                for (int rg = 0; rg < 4; ++rg)
                    plc[((wid * 3 + p) * 16 + hi * 4 + rg) * 17 + l15] = acc[p][rg];
        }

        // issue next-step G prefetch (cached; ~1 step of latency hiding)
        unsigned short gr2 = 0, gz2 = 0, gn2 = 0;
        if (s < 1023) {
            int g2 = dir ? (1022 - s) : (s + 1);
            const unsigned short* gp2 = gchunk0 + (size_t)g2 * gstride;
            gr2 = gp2[0]; gz2 = gp2[16]; gn2 = gp2[32];
        }

        __syncthreads();
        if (s > 0) {
#pragma unroll
            for (int w = 0; w < 4; ++w) {
                rsum += plc[((w * 3 + 0) * 16 + b_l) * 17 + j_l];
                zsum += plc[((w * 3 + 1) * 16 + b_l) * 17 + j_l];
                nsum += plc[((w * 3 + 2) * 16 + b_l) * 17 + j_l];
            }
        }

        float rv = sigm(rsum + bf2f(gr));
        float zv = sigm(zsum + bf2f(gz));
        float nv = tanh_fast(bf2f(gn) + rv * (nsum + bnh));
        float hn = (1.0f - zv) * nv + zv * h_old;
        h_old = hn;
        gr = gr2; gz = gz2; gn = gn2;

        // h tile store: contiguous 512B, write-through pairs
        if (s < 1023) {
            unsigned short hbv = f2bf(hn);
            unsigned int other = (unsigned int)(unsigned short)__shfl_xor((int)hbv, 1);
            if (!(tid & 1)) {
                size_t w32 = ((((size_t)(dir * 2 + par) * 2 + bg) * 64 + jg) * 128)
                             + b_l * 8 + (j_l >> 1);
                store_wt(hbuf32 + w32, (unsigned)hbv | (other << 16));
            }
        }
        // out: PLAIN store (L2 ack — off the critical path; evicts in bg)
        const int s_out = dir ? (1023 - s) : s;
        out[((size_t)(bb + b_l) * SS + s_out) * 2048 + dir * 1024 + jbase + j_l] = hn;
        if (s == 1023)
            out[(size_t)BB * SS * 2048 + (size_t)(bb + b_l) * 2048 +
                dir * 1024 + jbase + j_l] = hn;

        if (s < 1023) {
            // drain this wave's stores (h -> LLC, out -> L2), then publish
            asm volatile("s_waitcnt vmcnt(0)" ::: "memory");
            if (lane == 0)
                store_wt(&fl[jg * 4 + wid], (unsigned)(s + 1));
        }
    }
}

// =====================================================================
extern "C" void kernel_launch(void* const* d_in, const int* in_sizes, int n_in,
                              void* d_out, int out_size, void* d_ws, size_t ws_size,
                              hipStream_t stream)
{
    if (n_in < 15) return;
    const float* x      = (const float*)d_in[0];
    const float* Wi     = (const float*)d_in[1];
    const float* Wh     = (const float*)d_in[2];
    const float* Bg     = (const float*)d_in[3];
    const float* Wni    = (const float*)d_in[4];
    const float* Wnh    = (const float*)d_in[5];
    const float* Bni    = (const float*)d_in[6];
    const float* Bnh    = (const float*)d_in[7];
    const float* Winvi  = (const float*)d_in[8];
    const float* Winvh  = (const float*)d_in[9];
    const float* Binv   = (const float*)d_in[10];
    const float* Wninvi = (const float*)d_in[11];
    const float* Wninvh = (const float*)d_in[12];
    const float* Bninvi = (const float*)d_in[13];
    const float* Bninvh = (const float*)d_in[14];

    if (ws_size < WS_NEED) {
        hipMemsetAsync(d_out, 0, (size_t)out_size * 4, stream);
        return;
    }
    char* ws = (char*)d_ws;
    unsigned short* xb   = (unsigned short*)(ws + OFF_X);
    unsigned short* WinT = (unsigned short*)(ws + OFF_WINT);
    unsigned short* Wrec = (unsigned short*)(ws + OFF_WREC);
    float*          bias = (float*)(ws + OFF_BIAS);
    unsigned short* hbuf = (unsigned short*)(ws + OFF_H);
    unsigned int*   bar  = (unsigned int*)(ws + OFF_BAR);
    unsigned short* G    = (unsigned short*)(ws + OFF_G);

    hipMemsetAsync(ws + OFF_BAR, 0, SZ_BAR, stream);

    prep_kernel<<<4096, 256, 0, stream>>>(
        x, Wi, Wni, Winvi, Wninvi, Wh, Wnh, Winvh, Wninvh,
        Bg, Bni, Binv, Bninvi, xb, WinT, Wrec, bias);

    gemm_in<<<12288, 256, 0, stream>>>(xb, WinT, bias, G);

    const int smem_c = 98304 + 2 * (4 * 3 * 16 * 17) * 4;   // 124,416 B
    hipFuncSetAttribute(reinterpret_cast<const void*>(&gru_rec),
                        hipFuncAttributeMaxDynamicSharedMemorySize, smem_c);
    gru_rec<<<256, 256, smem_c, stream>>>(
        G, Wrec, Bnh, Bninvh, hbuf, (float*)d_out, bar);
}

// Round 5
// 3836.646 us; speedup vs baseline: 8.0665x; 1.7083x over previous
//
#include <hip/hip_runtime.h>
#include <cstdint>
#include <cstddef>

typedef __attribute__((ext_vector_type(8))) short s8v;          // 8 bf16
typedef __attribute__((ext_vector_type(4))) float f4v;
typedef __attribute__((ext_vector_type(4))) unsigned int u4v;

#define DEVFN __device__ __forceinline__

DEVFN unsigned short f2bf(float f) {
    unsigned int u = __builtin_bit_cast(unsigned int, f);
    return (unsigned short)((u + 0x7FFFu + ((u >> 16) & 1u)) >> 16);
}
DEVFN float bf2f(unsigned short h) {
    unsigned int u = ((unsigned int)h) << 16;
    return __builtin_bit_cast(float, u);
}
DEVFN float sigm(float x) { return 1.0f / (1.0f + __expf(-x)); }
DEVFN float tanh_fast(float x) { float e = __expf(2.0f * x); return 1.0f - 2.0f / (e + 1.0f); }

DEVFN u4v pack8(const unsigned short o[8]) {
    u4v v;
    v[0] = (unsigned)o[0] | ((unsigned)o[1] << 16);
    v[1] = (unsigned)o[2] | ((unsigned)o[3] << 16);
    v[2] = (unsigned)o[4] | ((unsigned)o[5] << 16);
    v[3] = (unsigned)o[6] | ((unsigned)o[7] << 16);
    return v;
}

// device-scope (LLC) write-through store — visible across XCDs, no fence.
DEVFN void store_wt(unsigned int* p, unsigned int v) {
    asm volatile("global_store_dword %0, %1, off sc0 sc1"
                 :: "v"(p), "v"(v) : "memory");
}
// LLC-direct flag read (bypasses stale L1/L2).
DEVFN unsigned poll_load(const unsigned int* p) {
    unsigned v;
    asm volatile("global_load_dword %0, %1, off sc0 sc1\n\t"
                 "s_waitcnt vmcnt(0)"
                 : "=v"(v) : "v"(p) : "memory");
    return v;
}
// 8x dwordx4 LLC-direct tile gather + drain.
DEVFN void gather_h(const void* p0, const void* p1,
                    u4v& a0, u4v& a1, u4v& a2, u4v& a3,
                    u4v& a4, u4v& a5, u4v& a6, u4v& a7) {
    asm volatile(
        "global_load_dwordx4 %0, %8, off sc0 sc1\n\t"
        "global_load_dwordx4 %1, %8, off offset:1024 sc0 sc1\n\t"
        "global_load_dwordx4 %2, %8, off offset:2048 sc0 sc1\n\t"
        "global_load_dwordx4 %3, %8, off offset:3072 sc0 sc1\n\t"
        "global_load_dwordx4 %4, %9, off sc0 sc1\n\t"
        "global_load_dwordx4 %5, %9, off offset:1024 sc0 sc1\n\t"
        "global_load_dwordx4 %6, %9, off offset:2048 sc0 sc1\n\t"
        "global_load_dwordx4 %7, %9, off offset:3072 sc0 sc1\n\t"
        "s_waitcnt vmcnt(0)"
        : "=&v"(a0), "=&v"(a1), "=&v"(a2), "=&v"(a3),
          "=&v"(a4), "=&v"(a5), "=&v"(a6), "=&v"(a7)
        : "v"(p0), "v"(p1)
        : "memory");
}

// ---------------- geometry ----------------
constexpr int BB = 32, SS = 1024, II = 512, HH = 1024;
constexpr int NCOL = 6144;

constexpr size_t OFF_X    = 0;                       // bf16 x   [32768][512]
constexpr size_t SZ_X     = (size_t)BB * SS * II * 2;
constexpr size_t OFF_WINT = OFF_X + SZ_X;            // bf16 WinT [6144][512]
constexpr size_t SZ_WINT  = (size_t)NCOL * II * 2;
constexpr size_t OFF_WREC = OFF_WINT + SZ_WINT;      // bf16 Wrec [2][3072][1024]
constexpr size_t SZ_WREC  = (size_t)2 * 3072 * HH * 2;
constexpr size_t OFF_BIAS = OFF_WREC + SZ_WREC;      // f32 [6144]
constexpr size_t SZ_BIAS  = (size_t)NCOL * 4;
// h tiles: [dir][buf][bg][jg(64)][b16(16)][j16(16)] bf16 — 512 B per tile
constexpr size_t OFF_H    = OFF_BIAS + SZ_BIAS;
constexpr size_t SZ_H     = (size_t)2 * 2 * 2 * 64 * 512;
constexpr size_t OFF_BAR  = OFF_H + SZ_H;            // flags [4 groups][64 jg][4 wave]
constexpr size_t SZ_BAR   = 4096;
// G layout: [s][dir][jg(64)][bg(2)][b16(16)][gate(3)][j(16)] bf16
constexpr size_t OFF_G    = OFF_BAR + SZ_BAR;
constexpr size_t SZ_G     = (size_t)SS * BB * NCOL * 2;
constexpr size_t WS_NEED  = OFF_G + SZ_G;            // ~455 MB

// gru_rec LDS layout
constexpr int WL_OFF = 0;          // 98304  weights
constexpr int PL_OFF = 98304;      // 26112  partials x2 parity
constexpr int GR_OFF = 124416;     // 6144   G ring, 4 slots x 1536B
constexpr int PF_OFF = 130560;     // 32     partial flags [2 par][4 wave]
constexpr int RD_OFF = 130592;     // 16     G ring ready[4]
constexpr int PG_OFF = 130608;     // 16     G ring progress[4 wave]
constexpr int SMEM_TOT = 130624;
constexpr int PLF = 4 * 3 * 16 * 17;   // floats per parity buffer

// =====================================================================
// prep
// =====================================================================
__global__ void prep_kernel(
    const float* __restrict__ x,
    const float* __restrict__ Wi, const float* __restrict__ Wni,
    const float* __restrict__ Winvi, const float* __restrict__ Wninvi,
    const float* __restrict__ Wh, const float* __restrict__ Wnh,
    const float* __restrict__ Winvh, const float* __restrict__ Wninvh,
    const float* __restrict__ Bg, const float* __restrict__ Bni,
    const float* __restrict__ Binv, const float* __restrict__ Bninvi,
    unsigned short* __restrict__ xb, unsigned short* __restrict__ WinT,
    unsigned short* __restrict__ Wrec, float* __restrict__ bias)
{
    constexpr int NX8  = (BB * SS * II) / 8;
    constexpr int NWI8 = (NCOL * II) / 8;
    constexpr int NWR8 = (2 * 3072 * HH) / 8;
    constexpr int TOT  = NX8 + NWI8 + NWR8 + NCOL;
    for (int i = blockIdx.x * blockDim.x + threadIdx.x; i < TOT;
         i += gridDim.x * blockDim.x) {
        if (i < NX8) {
            const float* sp = x + (size_t)i * 8;
            unsigned short o[8];
#pragma unroll
            for (int j = 0; j < 8; ++j) o[j] = f2bf(sp[j]);
            *(u4v*)(xb + (size_t)i * 8) = pack8(o);
        } else if (i < NX8 + NWI8) {
            int u = i - NX8;
            int n = u >> 6, k0 = (u & 63) * 8;
            const float* src; int stride;
            if (n < 2048)      { src = Wi + n;            stride = 2048; }
            else if (n < 3072) { src = Wni + (n - 2048);  stride = 1024; }
            else if (n < 5120) { src = Winvi + (n - 3072); stride = 2048; }
            else               { src = Wninvi + (n - 5120); stride = 1024; }
            unsigned short o[8];
#pragma unroll
            for (int j = 0; j < 8; ++j) o[j] = f2bf(src[(size_t)(k0 + j) * stride]);
            *(u4v*)(WinT + (size_t)n * 512 + k0) = pack8(o);
        } else if (i < NX8 + NWI8 + NWR8) {
            int u = i - NX8 - NWI8;
            int R = u >> 7, k0 = (u & 127) * 8;
            int dir = R / 3072, n = R % 3072;
            const float* src; int stride;
            if (n < 2048) { src = (dir ? Winvh : Wh) + n;          stride = 2048; }
            else          { src = (dir ? Wninvh : Wnh) + (n - 2048); stride = 1024; }
            unsigned short o[8];
#pragma unroll
            for (int j = 0; j < 8; ++j) o[j] = f2bf(src[(size_t)(k0 + j) * stride]);
            *(u4v*)(Wrec + (size_t)R * 1024 + k0) = pack8(o);
        } else {
            int c = i - NX8 - NWI8 - NWR8;
            int dir = c / 3072, cc = c % 3072;
            bias[c] = (cc < 2048) ? (dir ? Binv : Bg)[cc]
                                  : (dir ? Bninvi : Bni)[cc - 2048];
        }
    }
}

// =====================================================================
// gemm_in (unchanged)
// =====================================================================
#define GLL16(gp, lp) __builtin_amdgcn_global_load_lds( \
    (const __attribute__((address_space(1))) void*)(gp), \
    (__attribute__((address_space(3))) void*)(lp), 16, 0, 0)

__global__ __launch_bounds__(256, 2) void gemm_in(
    const unsigned short* __restrict__ xb,
    const unsigned short* __restrict__ WinT,
    const float* __restrict__ bias,
    unsigned short* __restrict__ G)
{
    __shared__ char smem[32768];
    char* As = smem;
    char* Bs = smem + 16384;
    const int tid = threadIdx.x, lane = tid & 63, wid = tid >> 6;
    int wg = blockIdx.x;
    int swz = (wg & 7) * 1536 + (wg >> 3);
    const int m0 = (swz & 255) * 128, n0 = (swz >> 8) * 128;
    const int l15 = lane & 15, hi = lane >> 4;
    const int mw = (wid & 1) * 64, nw = (wid >> 1) * 64;

    f4v acc[4][4] = {};

    const char* xrow = (const char*)xb;
    const char* wrow = (const char*)WinT;

    for (int kt = 0; kt < 8; ++kt) {
        const int kb0 = kt * 128;
#pragma unroll
        for (int r = 0; r < 4; ++r) {
            int q = wid * 4 + r;
            int o = q * 1024 + lane * 16;
            int row = o >> 7;
            int kbs = (o ^ ((row & 7) << 4)) & 127;
            GLL16(xrow + (size_t)(m0 + row) * 1024 + kb0 + kbs, As + q * 1024);
            GLL16(wrow + (size_t)(n0 + row) * 1024 + kb0 + kbs, Bs + q * 1024);
        }
        __syncthreads();
#pragma unroll
        for (int kc = 0; kc < 2; ++kc) {
            s8v a[4], b[4];
#pragma unroll
            for (int mt = 0; mt < 4; ++mt) {
                int row = mw + mt * 16 + l15;
                int off = (row << 7) + kc * 64 + hi * 16;
                a[mt] = *(const s8v*)(As + (off ^ ((row & 7) << 4)));
            }
#pragma unroll
            for (int nt = 0; nt < 4; ++nt) {
                int row = nw + nt * 16 + l15;
                int off = (row << 7) + kc * 64 + hi * 16;
                b[nt] = *(const s8v*)(Bs + (off ^ ((row & 7) << 4)));
            }
#pragma unroll
            for (int mt = 0; mt < 4; ++mt)
#pragma unroll
                for (int nt = 0; nt < 4; ++nt)
                    acc[mt][nt] = __builtin_amdgcn_mfma_f32_16x16x32_bf16(
                        a[mt], b[nt], acc[mt][nt], 0, 0, 0);
        }
        __syncthreads();
    }
#pragma unroll
    for (int mt = 0; mt < 4; ++mt) {
#pragma unroll
        for (int rg = 0; rg < 4; ++rg) {
            int m = m0 + mw + mt * 16 + hi * 4 + rg;
            int bi = m >> 10, si = m & 1023;
            int bg = bi >> 4, b16 = bi & 15;
#pragma unroll
            for (int nt = 0; nt < 4; ++nt) {
                int n = n0 + nw + nt * 16 + l15;
                int dir = (n >= 3072);
                int rem = n - dir * 3072;
                int gate = rem >> 10, col = rem & 1023;
                int jg = col >> 4, j = col & 15;
                size_t idx = (((((size_t)si * 2 + dir) * 64 + jg) * 2 + bg) * 16
                              + b16) * 48 + gate * 16 + j;
                G[idx] = f2bf(acc[mt][nt][rg] + bias[n]);
            }
        }
    }
}

// =====================================================================
// gru_rec: persistent bidirectional GRU recurrence, 256 blocks (1/CU),
// 320 threads: waves 0-3 compute, wave 4 = G prefetcher (own vmcnt!).
// No in-loop __syncthreads; partial reduce synced via LDS parity flags.
// =====================================================================
__global__ __launch_bounds__(320, 1) void gru_rec(
    const unsigned short* __restrict__ G,     // [s][dir][jg][bg][b16][gate][j]
    const unsigned short* __restrict__ Wrec,  // [2][3072][1024]
    const float* __restrict__ Bnh,
    const float* __restrict__ Bninvh,
    unsigned short* __restrict__ hbuf,        // bf16 tiles [dir][buf][bg][jg][16][16]
    float* __restrict__ out,                  // [32][1024][2048] + ht [32][2048]
    unsigned int* __restrict__ flags)         // [4 groups][64 jg][4 wave]
{
    extern __shared__ char smem[];
    char* wl = smem + WL_OFF;
    float* pl = (float*)(smem + PL_OFF);
    unsigned short* gring = (unsigned short*)(smem + GR_OFF);
    volatile int* pflag = (volatile int*)(smem + PF_OFF);
    volatile int* gready = (volatile int*)(smem + RD_OFF);
    volatile int* gprog  = (volatile int*)(smem + PG_OFF);

    const int tid = threadIdx.x, lane = tid & 63, wid = tid >> 6;
    const int bid = blockIdx.x;
    const int dir = bid >> 7, bg = (bid >> 6) & 1, jg = bid & 63;
    const int jbase = jg * 16, bb = bg * 16;
    const int l15 = lane & 15, hi = lane >> 4;
    unsigned int* fl = flags + ((dir * 2 + bg) << 8);

    // ---- prologue: init LDS flags; stage 3 weight panels into LDS ----
    if (tid < 4) { gready[tid] = -1; gprog[tid] = -1; }
    if (tid >= 4 && tid < 12) pflag[tid - 4] = -1;
    if (tid < 256) {
        const char* wsrc = (const char*)Wrec;
        for (int q = 0; q < 24; ++q) {
            int o = (q * 256 + tid) * 16;
            int c = o >> 11;
            int kb = (o ^ ((c & 7) << 4)) & 2047;
            int n = dir * 3072 + (c >> 4) * 1024 + jbase + (c & 15);
            *(u4v*)(wl + o) = *(const u4v*)(wsrc + (size_t)n * 2048 + kb);
        }
    }
    const int b_l = tid >> 4, j_l = tid & 15;
    const float bnh = (dir ? Bninvh : Bnh)[jbase + (j_l & 15)];
    __syncthreads();   // the ONLY block-wide barrier

    const size_t gstride_b = (size_t)2 * 64 * 2 * 768 * 2;   // bytes per s
    const char* gcb = (const char*)G + (((size_t)dir * 64 + jg) * 2 + bg) * 1536;

    if (wid == 4) {
        // ---------------- G prefetch wave ----------------
        char* grb = (char*)gring;
        for (int t = 0; t < 1024; ++t) {
            const int slot = t & 3;
            if (t >= 4) {
                int v;
                do { v = gprog[lane & 3]; } while (!__all(v >= t - 4));
            }
            const int gpos = dir ? (1023 - t) : t;
            const char* src = gcb + (size_t)gpos * gstride_b + lane * 32;
            if (lane < 48) {
                u4v d0 = *(const u4v*)(src);
                u4v d1 = *(const u4v*)(src + 16);
                *(u4v*)(grb + slot * 1536 + lane * 32) = d0;
                *(u4v*)(grb + slot * 1536 + lane * 32 + 16) = d1;
            }
            asm volatile("s_waitcnt lgkmcnt(0) vmcnt(0)" ::: "memory");
            if (lane == 0) gready[slot] = t;
        }
        return;
    }

    // ---------------- compute waves (0..3) ----------------
    float h_old = 0.0f;
    unsigned int* hbuf32 = (unsigned int*)hbuf;

    for (int s = 0; s < 1024; ++s) {
        const int par = s & 1;
        float* plc = pl + par * PLF;

        // ---- G for this step from the LDS ring ----
        const int slot = s & 3;
        {
            int r;
            do { r = gready[slot]; } while (r != s);
        }
        asm volatile("" ::: "memory");
        const int gb = slot * 768 + b_l * 48 + j_l;
        unsigned short gr = gring[gb];
        unsigned short gz = gring[gb + 16];
        unsigned short gn = gring[gb + 32];
        asm volatile("s_waitcnt lgkmcnt(0)" ::: "memory");
        if (lane == 0) gprog[wid] = s;

        float rsum = 0.f, zsum = 0.f, nsum = 0.f;
        if (s > 0) {
            // ---- wave-subset poll: 16 producer blocks x 4 wave-flags ----
            const unsigned tgt = (unsigned)s;
            const unsigned int* fp = fl + wid * 64 + lane;
            unsigned v;
            do { v = poll_load(fp); } while (!__all(v >= tgt));

            // ---- gather h tiles (contiguous 512B per producer block) ----
            const int rbuf = par ^ 1;
            const char* hb = (const char*)hbuf +
                ((((size_t)(dir * 2 + rbuf) * 2 + bg) * 64)
                 + (size_t)(wid * 16 + (hi >> 1))) * 512
                + l15 * 32 + (hi & 1) * 16;
            u4v u[8];
            gather_h(hb, hb + 4096, u[0], u[1], u[2], u[3],
                     u[4], u[5], u[6], u[7]);

            f4v acc[3] = {};
#pragma unroll
            for (int p = 0; p < 3; ++p) {
                int c = p * 16 + l15;
                int cbase = c << 11;
                int sw = (c & 7) << 4;
#pragma unroll
                for (int kc = 0; kc < 8; ++kc) {
                    int off = cbase + (wid << 9) + kc * 64 + hi * 16;
                    s8v bf = *(const s8v*)(wl + (off ^ sw));
                    acc[p] = __builtin_amdgcn_mfma_f32_16x16x32_bf16(
                        __builtin_bit_cast(s8v, u[kc]), bf, acc[p], 0, 0, 0);
                }
            }
#pragma unroll
            for (int p = 0; p < 3; ++p)
#pragma unroll
                for (int rg = 0; rg < 4; ++rg)
                    plc[((wid * 3 + p) * 16 + hi * 4 + rg) * 17 + l15] = acc[p][rg];
            asm volatile("s_waitcnt lgkmcnt(0)" ::: "memory");
            if (lane == 0) pflag[par * 4 + wid] = s;

            // ---- barrier-free reduce sync: wait all 4 compute waves ----
            {
                int f0, f1, f2, f3;
                do {
                    f0 = pflag[par * 4 + 0]; f1 = pflag[par * 4 + 1];
                    f2 = pflag[par * 4 + 2]; f3 = pflag[par * 4 + 3];
                } while (f0 < s || f1 < s || f2 < s || f3 < s);
            }
            asm volatile("" ::: "memory");
#pragma unroll
            for (int w = 0; w < 4; ++w) {
                rsum += plc[((w * 3 + 0) * 16 + b_l) * 17 + j_l];
                zsum += plc[((w * 3 + 1) * 16 + b_l) * 17 + j_l];
                nsum += plc[((w * 3 + 2) * 16 + b_l) * 17 + j_l];
            }
        }

        float rv = sigm(rsum + bf2f(gr));
        float zv = sigm(zsum + bf2f(gz));
        float nv = tanh_fast(bf2f(gn) + rv * (nsum + bnh));
        float hn = (1.0f - zv) * nv + zv * h_old;
        h_old = hn;

        // h tile store: contiguous 512B, write-through pairs
        if (s < 1023) {
            unsigned short hbv = f2bf(hn);
            unsigned int other = (unsigned int)(unsigned short)__shfl_xor((int)hbv, 1);
            if (!(tid & 1)) {
                size_t w32 = ((((size_t)(dir * 2 + par) * 2 + bg) * 64 + jg) * 128)
                             + b_l * 8 + (j_l >> 1);
                store_wt(hbuf32 + w32, (unsigned)hbv | (other << 16));
            }
        }
        // out: plain cached store (L2 ack)
        const int s_out = dir ? (1023 - s) : s;
        out[((size_t)(bb + b_l) * SS + s_out) * 2048 + dir * 1024 + jbase + j_l] = hn;
        if (s == 1023)
            out[(size_t)BB * SS * 2048 + (size_t)(bb + b_l) * 2048 +
                dir * 1024 + jbase + j_l] = hn;

        if (s < 1023) {
            // drain THIS wave's stores (h->LLC ack; no G loads here anymore)
            asm volatile("s_waitcnt vmcnt(0)" ::: "memory");
            if (lane == 0)
                store_wt(&fl[jg * 4 + wid], (unsigned)(s + 1));
        }
    }
}

// =====================================================================
extern "C" void kernel_launch(void* const* d_in, const int* in_sizes, int n_in,
                              void* d_out, int out_size, void* d_ws, size_t ws_size,
                              hipStream_t stream)
{
    if (n_in < 15) return;
    const float* x      = (const float*)d_in[0];
    const float* Wi     = (const float*)d_in[1];
    const float* Wh     = (const float*)d_in[2];
    const float* Bg     = (const float*)d_in[3];
    const float* Wni    = (const float*)d_in[4];
    const float* Wnh    = (const float*)d_in[5];
    const float* Bni    = (const float*)d_in[6];
    const float* Bnh    = (const float*)d_in[7];
    const float* Winvi  = (const float*)d_in[8];
    const float* Winvh  = (const float*)d_in[9];
    const float* Binv   = (const float*)d_in[10];
    const float* Wninvi = (const float*)d_in[11];
    const float* Wninvh = (const float*)d_in[12];
    const float* Bninvi = (const float*)d_in[13];
    const float* Bninvh = (const float*)d_in[14];

    if (ws_size < WS_NEED) {
        hipMemsetAsync(d_out, 0, (size_t)out_size * 4, stream);
        return;
    }
    char* ws = (char*)d_ws;
    unsigned short* xb   = (unsigned short*)(ws + OFF_X);
    unsigned short* WinT = (unsigned short*)(ws + OFF_WINT);
    unsigned short* Wrec = (unsigned short*)(ws + OFF_WREC);
    float*          bias = (float*)(ws + OFF_BIAS);
    unsigned short* hbuf = (unsigned short*)(ws + OFF_H);
    unsigned int*   bar  = (unsigned int*)(ws + OFF_BAR);
    unsigned short* G    = (unsigned short*)(ws + OFF_G);

    hipMemsetAsync(ws + OFF_BAR, 0, SZ_BAR, stream);

    prep_kernel<<<4096, 256, 0, stream>>>(
        x, Wi, Wni, Winvi, Wninvi, Wh, Wnh, Winvh, Wninvh,
        Bg, Bni, Binv, Bninvi, xb, WinT, Wrec, bias);

    gemm_in<<<12288, 256, 0, stream>>>(xb, WinT, bias, G);

    hipFuncSetAttribute(reinterpret_cast<const void*>(&gru_rec),
                        hipFuncAttributeMaxDynamicSharedMemorySize, SMEM_TOT);
    gru_rec<<<256, 320, SMEM_TOT, stream>>>(
        G, Wrec, Bnh, Bninvh, hbuf, (float*)d_out, bar);
}